// Round 1
// baseline (1017.764 us; speedup 1.0000x reference)
//
#include <hip/hip_runtime.h>

#define NN 52500
#define NP 36500            // nodes with children (levels 0..4) = parents
#define E0 500              // edge e corresponds to src node n = e + 500
#define NEDGE 52000
#define NBINS 160           // 5 edge-levels x 32 matrices

__device__ __forceinline__ float sigmoidf_(float x) { return 1.f / (1.f + __expf(-x)); }
__device__ __forceinline__ float tanhf_(float x) {
    float e = __expf(-2.f * fabsf(x));
    return copysignf((1.f - e) / (1.f + e), x);
}

typedef __attribute__((ext_vector_type(8))) short bf16x8;
typedef __attribute__((ext_vector_type(4))) float f32x4;

__device__ __forceinline__ unsigned short f2bf_rne(float f) {
    unsigned int u = __float_as_uint(f);
    u += 0x7FFF + ((u >> 16) & 1);
    return (unsigned short)(u >> 16);
}

// load 8 consecutive f32, split each into bf16 hi + bf16 lo (compensated precision ~2^-17)
__device__ __forceinline__ void load_split(const float* p, bf16x8& hi, bf16x8& lo) {
    float4 a = *(const float4*)p;
    float4 b = *(const float4*)(p + 4);
    float v[8] = {a.x, a.y, a.z, a.w, b.x, b.y, b.z, b.w};
#pragma unroll
    for (int j = 0; j < 8; ++j) {
        unsigned short hu = f2bf_rne(v[j]);
        float hf = __uint_as_float((unsigned int)hu << 16);
        hi[j] = (short)hu;
        lo[j] = (short)f2bf_rne(v[j] - hf);
    }
}

__global__ __launch_bounds__(256) void zero_kernel(float* __restrict__ p, int n4) {
    int i = blockIdx.x * 256 + threadIdx.x;
    if (i < n4) ((float4*)p)[i] = (float4){0.f, 0.f, 0.f, 0.f};
}

// -------- one-time edge binning by (level, matrix_id): 160 bins, single block --------
__global__ __launch_bounds__(1024) void bin_kernel(const int* __restrict__ mat_id,
                                                   int* __restrict__ bin_off,
                                                   int* __restrict__ ord) {
    __shared__ int cnt[NBINS];
    __shared__ int coff[NBINS + 1];
    for (int i = threadIdx.x; i < NBINS; i += 1024) cnt[i] = 0;
    __syncthreads();
    for (int e = threadIdx.x; e < NEDGE; e += 1024) {
        int L = (e >= 2000) + (e >= 8000) + (e >= 20000) + (e >= 36000);
        atomicAdd(&cnt[L * 32 + mat_id[e]], 1);
    }
    __syncthreads();
    if (threadIdx.x == 0) {
        int s = 0;
        for (int i = 0; i < NBINS; ++i) { coff[i] = s; s += cnt[i]; }
        coff[NBINS] = s;
    }
    __syncthreads();
    for (int i = threadIdx.x; i <= NBINS; i += 1024) bin_off[i] = coff[i];
    for (int i = threadIdx.x; i < NBINS; i += 1024) cnt[i] = coff[i];   // reuse as cursor
    __syncthreads();
    for (int e = threadIdx.x; e < NEDGE; e += 1024) {
        int L = (e >= 2000) + (e >= 8000) + (e >= 20000) + (e >= 36000);
        int pos = atomicAdd(&cnt[L * 32 + mat_id[e]], 1);
        ord[pos] = e;
    }
}

// x_f = x @ W_f^T + b_f for nodes 0..NP-1, f32 out, compensated bf16 MFMA
__global__ __launch_bounds__(256) void xfproj_kernel(
    const float* __restrict__ x, const float* __restrict__ Wf,
    const float* __restrict__ bfp, float* __restrict__ xf)
{
    int wave = threadIdx.x >> 6, lane = threadIdx.x & 63;
    int l15 = lane & 15, quad = lane >> 4;
    int rowBase = blockIdx.x * 64 + wave * 16;

    int arow = rowBase + l15;
    if (arow >= NP) arow = NP - 1;
    const float* ap = x + (size_t)arow * 128 + quad * 8;
    bf16x8 ahi[4], alo[4];
#pragma unroll
    for (int kt = 0; kt < 4; ++kt) load_split(ap + kt * 32, ahi[kt], alo[kt]);

    f32x4 acc[4];
#pragma unroll
    for (int ct = 0; ct < 4; ++ct) acc[ct] = (f32x4){0.f, 0.f, 0.f, 0.f};

#pragma unroll
    for (int ct = 0; ct < 4; ++ct) {
        int col = ct * 16 + l15;
        const float* bp = Wf + (size_t)col * 128 + quad * 8;
#pragma unroll
        for (int kt = 0; kt < 4; ++kt) {
            bf16x8 bhi, blo;
            load_split(bp + kt * 32, bhi, blo);
            acc[ct] = __builtin_amdgcn_mfma_f32_16x16x32_bf16(ahi[kt], bhi, acc[ct], 0, 0, 0);
            acc[ct] = __builtin_amdgcn_mfma_f32_16x16x32_bf16(ahi[kt], blo, acc[ct], 0, 0, 0);
            acc[ct] = __builtin_amdgcn_mfma_f32_16x16x32_bf16(alo[kt], bhi, acc[ct], 0, 0, 0);
        }
    }

    // C/D: col = lane&15 (+16*ct), row = quad*4 + reg
#pragma unroll
    for (int ct = 0; ct < 4; ++ct) {
        int col = ct * 16 + l15;
        float bias = bfp[col];
#pragma unroll
        for (int r = 0; r < 4; ++r) {
            int n = rowBase + quad * 4 + r;
            if (n < NP) xf[(size_t)n * 64 + col] = acc[ct][r] + bias;
        }
    }
}

// per level: x_iou (192 cols, in-register) + Uh_sum/fc_sum -> cell -> h,c (f32 to d_out)
__global__ __launch_bounds__(256) void projcell_kernel(
    const float* __restrict__ x, const float* __restrict__ Wiou,
    const float* __restrict__ biou,
    const float* __restrict__ uh, const float* __restrict__ fcs,
    float* __restrict__ h_all, float* __restrict__ c_all,
    int s0, int s1, int read_sums)
{
    int wave = threadIdx.x >> 6, lane = threadIdx.x & 63;
    int l15 = lane & 15, quad = lane >> 4;
    int rowBase = blockIdx.x * 64 + wave * 16;    // relative to s0

    int arow = s0 + rowBase + l15;
    if (arow >= s1) arow = s1 - 1;
    const float* ap = x + (size_t)arow * 128 + quad * 8;
    bf16x8 ahi[4], alo[4];
#pragma unroll
    for (int kt = 0; kt < 4; ++kt) load_split(ap + kt * 32, ahi[kt], alo[kt]);

    f32x4 acc[12];
#pragma unroll
    for (int ct = 0; ct < 12; ++ct) acc[ct] = (f32x4){0.f, 0.f, 0.f, 0.f};

#pragma unroll
    for (int ct = 0; ct < 12; ++ct) {
        int col = ct * 16 + l15;
        const float* bp = Wiou + (size_t)col * 128 + quad * 8;
#pragma unroll
        for (int kt = 0; kt < 4; ++kt) {
            bf16x8 bhi, blo;
            load_split(bp + kt * 32, bhi, blo);
            acc[ct] = __builtin_amdgcn_mfma_f32_16x16x32_bf16(ahi[kt], bhi, acc[ct], 0, 0, 0);
            acc[ct] = __builtin_amdgcn_mfma_f32_16x16x32_bf16(ahi[kt], blo, acc[ct], 0, 0, 0);
            acc[ct] = __builtin_amdgcn_mfma_f32_16x16x32_bf16(alo[kt], bhi, acc[ct], 0, 0, 0);
        }
    }

    // lane (l15,quad) holds, for node row quad*4+r, h-cols j = 16g + l15 (g=0..3):
    //   i = acc[g], o = acc[4+g], u = acc[8+g]
#pragma unroll
    for (int g = 0; g < 4; ++g) {
        int j = g * 16 + l15;
        float bi = biou[j], bo = biou[64 + j], bu = biou[128 + j];
#pragma unroll
        for (int r = 0; r < 4; ++r) {
            int n = s0 + rowBase + quad * 4 + r;
            if (n < s1) {
                float iv = acc[g][r] + bi;
                float ov = acc[4 + g][r] + bo;
                float uv = acc[8 + g][r] + bu;
                float ui = 0.f, uo = 0.f, uu = 0.f, fc0 = 0.f;
                if (read_sums) {
                    size_t b = (size_t)n * 192;
                    ui = uh[b + j]; uo = uh[b + 64 + j]; uu = uh[b + 128 + j];
                    fc0 = fcs[(size_t)n * 64 + j];
                }
                float c = sigmoidf_(iv + ui) * tanhf_(uv + uu) + fc0;
                float h = sigmoidf_(ov + uo) * tanhf_(c);
                h_all[(size_t)n * 64 + j] = h;
                c_all[(size_t)n * 64 + j] = c;
            }
        }
    }
}

// -------- grouped edge kernel: one (level,mid) bin per block, U staged in LDS,
// -------- each wave register-blocks 8 edges against the shared U tile.
__global__ __launch_bounds__(256) void edge_group_kernel(
    const float* __restrict__ h_all, const float* __restrict__ c_all,
    const float* __restrict__ xf,
    float* __restrict__ uh, float* __restrict__ fcs,
    const float* __restrict__ Uiou, const float* __restrict__ Ufm,
    const int* __restrict__ edge_dst,
    const int* __restrict__ bin_off, const int* __restrict__ ord,
    int lvl /*0..4 = edge-level-1*/, int NB)
{
    __shared__ float sU[16384];        // U_iou [64][192] | U_f [64][64]  (64 KB)
    __shared__ float hbuf[4][8][64];   // per-wave h rows for 8 edges      (8 KB)

    int bin = lvl * 32 + (blockIdx.x & 31);
    int bslot = blockIdx.x >> 5;
    int off = bin_off[bin];
    int cnt = bin_off[bin + 1] - off;
    if (bslot * 32 >= cnt) return;     // block-uniform: safe before barrier

    int mid = bin & 31;
    {
        const float4* s0p = (const float4*)(Uiou + (size_t)mid * 12288);
        float4* d0 = (float4*)sU;
        for (int i = threadIdx.x; i < 3072; i += 256) d0[i] = s0p[i];
        const float4* s1p = (const float4*)(Ufm + (size_t)mid * 4096);
        float4* d1 = (float4*)(sU + 12288);
        for (int i = threadIdx.x; i < 1024; i += 256) d1[i] = s1p[i];
    }
    __syncthreads();

    int wid = threadIdx.x >> 6, lane = threadIdx.x & 63;
    bool isf = (lane >= 48);
    // lanes 0..47: U_iou cols 4L..4L+3 (192); lanes 48..63: U_f cols 4(L-48)..+3 (64)
    int cb = isf ? 4 * (lane - 48) : 4 * lane;
    int ubase = isf ? (12288 + cb) : cb;
    int ustride = isf ? 64 : 192;

    for (int j0 = bslot * 32 + wid * 8; j0 < cnt; j0 += NB * 32) {
        int eidx[8], dstv[8];
#pragma unroll
        for (int q = 0; q < 8; ++q) {
            int jq = j0 + q; if (jq > cnt - 1) jq = cnt - 1;   // pad: recompute last edge, skip scatter
            int e = ord[off + jq];
            eidx[q] = e;
            dstv[q] = edge_dst[e];
            hbuf[wid][q][lane] = h_all[(size_t)(e + E0) * 64 + lane];  // wave-private, in-order DS
        }

        float a0[8], a1[8], a2[8], a3[8];
#pragma unroll
        for (int q = 0; q < 8; ++q) a0[q] = a1[q] = a2[q] = a3[q] = 0.f;

        for (int kg = 0; kg < 16; ++kg) {
            float4 hv[8];
#pragma unroll
            for (int q = 0; q < 8; ++q) hv[q] = *(const float4*)&hbuf[wid][q][kg * 4];
            const float* up = &sU[ubase + kg * 4 * ustride];
#pragma unroll
            for (int t = 0; t < 4; ++t) {
                float4 u = *(const float4*)(up + t * ustride);  // shared by all 8 edges
#pragma unroll
                for (int q = 0; q < 8; ++q) {
                    float s = (t == 0) ? hv[q].x : (t == 1) ? hv[q].y : (t == 2) ? hv[q].z : hv[q].w;
                    a0[q] = fmaf(s, u.x, a0[q]);
                    a1[q] = fmaf(s, u.y, a1[q]);
                    a2[q] = fmaf(s, u.z, a2[q]);
                    a3[q] = fmaf(s, u.w, a3[q]);
                }
            }
        }

#pragma unroll
        for (int q = 0; q < 8; ++q) {
            if (j0 + q < cnt) {
                int e = eidx[q], dst = dstv[q];
                if (isf) {
                    size_t d = (size_t)dst * 64 + cb;   // xf and fcs share indexing
                    float4 cv = *(const float4*)&c_all[(size_t)(e + E0) * 64 + cb];
                    atomicAdd(&fcs[d + 0], sigmoidf_(xf[d + 0] + a0[q]) * cv.x);
                    atomicAdd(&fcs[d + 1], sigmoidf_(xf[d + 1] + a1[q]) * cv.y);
                    atomicAdd(&fcs[d + 2], sigmoidf_(xf[d + 2] + a2[q]) * cv.z);
                    atomicAdd(&fcs[d + 3], sigmoidf_(xf[d + 3] + a3[q]) * cv.w);
                } else {
                    size_t d = (size_t)dst * 192 + cb;
                    atomicAdd(&uh[d + 0], a0[q]);
                    atomicAdd(&uh[d + 1], a1[q]);
                    atomicAdd(&uh[d + 2], a2[q]);
                    atomicAdd(&uh[d + 3], a3[q]);
                }
            }
        }
    }
}

// -------- fallback (ws too small for bin tables): original per-edge kernel --------
__global__ __launch_bounds__(256) void edge_kernel(
    const float* __restrict__ h_all, const float* __restrict__ c_all,
    const float* __restrict__ xf,
    float* __restrict__ uh, float* __restrict__ fcs,
    const float* __restrict__ Uiou, const float* __restrict__ Ufm,
    const int* __restrict__ edge_dst, const int* __restrict__ mat_id,
    int s0, int s1)
{
    __shared__ float hbuf[4][64];
    __shared__ float cbuf[4][64];
    int wid = threadIdx.x >> 6, lane = threadIdx.x & 63;
    int n = s0 + blockIdx.x * 4 + wid;
    if (n >= s1) return;

    hbuf[wid][lane] = h_all[(size_t)n * 64 + lane];
    cbuf[wid][lane] = c_all[(size_t)n * 64 + lane];

    int e = n - E0;
    int dst = edge_dst[e];
    int mid = mat_id[e];

    bool isf = (lane >= 48);
    int cb = isf ? 4 * (lane - 48) : 4 * lane;
    const float* p = isf ? (Ufm + (size_t)mid * 4096 + cb)
                         : (Uiou + (size_t)mid * 12288 + cb);
    int stride = isf ? 64 : 192;

    float a0 = 0.f, a1 = 0.f, a2 = 0.f, a3 = 0.f;
    for (int k = 0; k < 64; k += 4) {
        float4 hv = *(const float4*)&hbuf[wid][k];
#pragma unroll
        for (int t = 0; t < 4; ++t) {
            float4 u = *(const float4*)p;
            p += stride;
            float hvt = ((const float*)&hv)[t];
            a0 += hvt * u.x; a1 += hvt * u.y; a2 += hvt * u.z; a3 += hvt * u.w;
        }
    }

    if (isf) {
        size_t d = (size_t)dst * 64 + cb;
        float4 cv = *(const float4*)&cbuf[wid][cb];
        atomicAdd(&fcs[d + 0], sigmoidf_(xf[d + 0] + a0) * cv.x);
        atomicAdd(&fcs[d + 1], sigmoidf_(xf[d + 1] + a1) * cv.y);
        atomicAdd(&fcs[d + 2], sigmoidf_(xf[d + 2] + a2) * cv.z);
        atomicAdd(&fcs[d + 3], sigmoidf_(xf[d + 3] + a3) * cv.w);
    } else {
        size_t d = (size_t)dst * 192 + cb;
        atomicAdd(&uh[d + 0], a0);
        atomicAdd(&uh[d + 1], a1);
        atomicAdd(&uh[d + 2], a2);
        atomicAdd(&uh[d + 3], a3);
    }
}

extern "C" void kernel_launch(void* const* d_in, const int* in_sizes, int n_in,
                              void* d_out, int out_size, void* d_ws, size_t ws_size,
                              hipStream_t stream) {
    const float* x      = (const float*)d_in[0];
    // d_in[1] = edge_src == arange(500, 52500) -> unused
    const int* edge_dst = (const int*)d_in[2];
    const int* mat_id   = (const int*)d_in[3];
    const float* Wiou   = (const float*)d_in[4];
    const float* biou   = (const float*)d_in[5];
    const float* Wf     = (const float*)d_in[6];
    const float* bfp    = (const float*)d_in[7];
    const float* Uiou   = (const float*)d_in[8];
    const float* Ufm    = (const float*)d_in[9];

    // ws (f32): [uh: NP*192][fcs: NP*64][xf: NP*64][bin_off: 192 ints][ord: 52000 ints]
    float* uh  = (float*)d_ws;
    float* fcs = uh + (size_t)NP * 192;
    float* xf  = fcs + (size_t)NP * 64;
    int* bin_off = (int*)(xf + (size_t)NP * 64);
    int* ord = bin_off + 192;

    size_t need = (size_t)NP * 320 * 4 + (size_t)(192 + NEDGE) * 4;
    int grouped = (ws_size >= need) ? 1 : 0;

    float* out_h = (float*)d_out;            // f32 output: h then c
    float* out_c = out_h + (size_t)NN * 64;

    // zero uh+fcs (contiguous: NP*256 floats)
    int n4 = (int)((size_t)NP * 256 / 4);
    zero_kernel<<<(n4 + 255) / 256, 256, 0, stream>>>(uh, n4);

    if (grouped)
        bin_kernel<<<1, 1024, 0, stream>>>(mat_id, bin_off, ord);

    xfproj_kernel<<<(NP + 63) / 64, 256, 0, stream>>>(x, Wf, bfp, xf);

    static const int noff[7] = {0, 500, 2500, 8500, 20500, 36500, 52500};
    for (int l = 5; l >= 0; --l) {
        int s0 = noff[l], s1 = noff[l + 1], nl = s1 - s0;
        projcell_kernel<<<(nl + 63) / 64, 256, 0, stream>>>(
            x, Wiou, biou, uh, fcs, out_h, out_c, s0, s1, (l != 5) ? 1 : 0);
        if (l >= 1) {
            if (grouped) {
                int NB = (nl + 1023) >> 10; if (NB < 1) NB = 1;
                edge_group_kernel<<<NB * 32, 256, 0, stream>>>(
                    out_h, out_c, xf, uh, fcs, Uiou, Ufm,
                    edge_dst, bin_off, ord, l - 1, NB);
            } else {
                edge_kernel<<<(nl + 3) / 4, 256, 0, stream>>>(
                    out_h, out_c, xf, uh, fcs, Uiou, Ufm, edge_dst, mat_id, s0, s1);
            }
        }
    }
}

// Round 2
// 488.458 us; speedup vs baseline: 2.0836x; 2.0836x over previous
//
#include <hip/hip_runtime.h>

#define NN 52500
#define NP 36500            // nodes with children (levels 0..4) = parents
#define E0 500              // edge e corresponds to src node n = e + 500
#define NEDGE 52000
#define NBINS 160           // 5 edge-levels x 32 matrices
#define MAXEL 16000         // max edges in one level

__device__ __forceinline__ float sigmoidf_(float x) { return 1.f / (1.f + __expf(-x)); }
__device__ __forceinline__ float tanhf_(float x) {
    float e = __expf(-2.f * fabsf(x));
    return copysignf((1.f - e) / (1.f + e), x);
}

typedef __attribute__((ext_vector_type(8))) short bf16x8;
typedef __attribute__((ext_vector_type(4))) float f32x4;

__device__ __forceinline__ unsigned short f2bf_rne(float f) {
    unsigned int u = __float_as_uint(f);
    u += 0x7FFF + ((u >> 16) & 1);
    return (unsigned short)(u >> 16);
}

// load 8 consecutive f32, split each into bf16 hi + bf16 lo (compensated precision ~2^-17)
__device__ __forceinline__ void load_split(const float* p, bf16x8& hi, bf16x8& lo) {
    float4 a = *(const float4*)p;
    float4 b = *(const float4*)(p + 4);
    float v[8] = {a.x, a.y, a.z, a.w, b.x, b.y, b.z, b.w};
#pragma unroll
    for (int j = 0; j < 8; ++j) {
        unsigned short hu = f2bf_rne(v[j]);
        float hf = __uint_as_float((unsigned int)hu << 16);
        hi[j] = (short)hu;
        lo[j] = (short)f2bf_rne(v[j] - hf);
    }
}

__global__ __launch_bounds__(256) void zero_kernel(float* __restrict__ p, int n4) {
    int i = blockIdx.x * 256 + threadIdx.x;
    if (i < n4) ((float4*)p)[i] = (float4){0.f, 0.f, 0.f, 0.f};
}

// -------- one-time edge binning by (level, matrix_id): 160 bins, single block --------
__global__ __launch_bounds__(1024) void bin_kernel(const int* __restrict__ mat_id,
                                                   int* __restrict__ bin_off,
                                                   int* __restrict__ ord) {
    __shared__ int cnt[NBINS];
    __shared__ int coff[NBINS + 1];
    for (int i = threadIdx.x; i < NBINS; i += 1024) cnt[i] = 0;
    __syncthreads();
    for (int e = threadIdx.x; e < NEDGE; e += 1024) {
        int L = (e >= 2000) + (e >= 8000) + (e >= 20000) + (e >= 36000);
        atomicAdd(&cnt[L * 32 + mat_id[e]], 1);
    }
    __syncthreads();
    if (threadIdx.x == 0) {
        int s = 0;
        for (int i = 0; i < NBINS; ++i) { coff[i] = s; s += cnt[i]; }
        coff[NBINS] = s;
    }
    __syncthreads();
    for (int i = threadIdx.x; i <= NBINS; i += 1024) bin_off[i] = coff[i];
    for (int i = threadIdx.x; i < NBINS; i += 1024) cnt[i] = coff[i];   // reuse as cursor
    __syncthreads();
    for (int e = threadIdx.x; e < NEDGE; e += 1024) {
        int L = (e >= 2000) + (e >= 8000) + (e >= 20000) + (e >= 36000);
        int pos = atomicAdd(&cnt[L * 32 + mat_id[e]], 1);
        ord[pos] = e;
    }
}

// -------- CSR-by-dst build: hist -> scan -> fill (once per run) --------
__global__ __launch_bounds__(256) void hist_kernel(const int* __restrict__ edge_dst,
                                                   int* __restrict__ cnt) {
    int e = blockIdx.x * 256 + threadIdx.x;
    if (e < NEDGE) atomicAdd(&cnt[edge_dst[e]], 1);
}

// reads counts from cntcur, writes exclusive offsets to off AND rewrites cntcur to offsets
__global__ __launch_bounds__(1024) void scan_kernel(int* __restrict__ cntcur,
                                                    int* __restrict__ off) {
    __shared__ int part[1024];
    int t = threadIdx.x;
    int lo = t * 36, hi = lo + 36;
    if (lo > NP) lo = NP;
    if (hi > NP) hi = NP;
    int s = 0;
    for (int i = lo; i < hi; ++i) s += cntcur[i];
    part[t] = s;
    __syncthreads();
    for (int d = 1; d < 1024; d <<= 1) {
        int v = (t >= d) ? part[t - d] : 0;
        __syncthreads();
        part[t] += v;
        __syncthreads();
    }
    int run = part[t] - s;   // exclusive prefix
    for (int i = lo; i < hi; ++i) {
        int cv = cntcur[i];
        off[i] = run;
        cntcur[i] = run;     // becomes the fill cursor
        run += cv;
    }
    if (t == 1023) off[NP] = part[1023];
}

__global__ __launch_bounds__(256) void fill_kernel(const int* __restrict__ edge_dst,
                                                   int* __restrict__ cursor,
                                                   int* __restrict__ childList) {
    int e = blockIdx.x * 256 + threadIdx.x;
    if (e < NEDGE) {
        int pos = atomicAdd(&cursor[edge_dst[e]], 1);
        childList[pos] = e;
    }
}

// -------- one-time U pack: [32 mids][hi 16K | lo 16K] bf16 MFMA-B fragments --------
// frag f = ct*2+kt (ct 0..15, kt 0..1); elem(lane,j) = U[kt*32+(lane>>4)*8+j][ct*16+(lane&15)]
// cols 0..191 = U_iou, 192..255 = U_f
__global__ __launch_bounds__(256) void upack_kernel(
    const float* __restrict__ Uiou, const float* __restrict__ Ufm,
    unsigned short* __restrict__ Upack)
{
    int mid = blockIdx.x;
    unsigned short* dhi = Upack + (size_t)mid * 32768;
    unsigned short* dlo = dhi + 16384;
    for (int p0 = threadIdx.x * 8; p0 < 16384; p0 += 2048) {
        int f = p0 >> 9;
        int lane = (p0 >> 3) & 63;
        int kt = f & 1, ct = f >> 1;
        int kbase = kt * 32 + (lane >> 4) * 8;
        int col = ct * 16 + (lane & 15);
#pragma unroll
        for (int j = 0; j < 8; ++j) {
            int k = kbase + j;
            float v = (col < 192) ? Uiou[(size_t)mid * 12288 + k * 192 + col]
                                  : Ufm[(size_t)mid * 4096 + k * 64 + (col - 192)];
            unsigned short hu = f2bf_rne(v);
            float hf = __uint_as_float((unsigned int)hu << 16);
            dhi[p0 + j] = hu;
            dlo[p0 + j] = f2bf_rne(v - hf);
        }
    }
}

// x_f = x @ W_f^T + b_f for nodes 0..NP-1, f32 out, compensated bf16 MFMA
__global__ __launch_bounds__(256) void xfproj_kernel(
    const float* __restrict__ x, const float* __restrict__ Wf,
    const float* __restrict__ bfp, float* __restrict__ xf)
{
    int wave = threadIdx.x >> 6, lane = threadIdx.x & 63;
    int l15 = lane & 15, quad = lane >> 4;
    int rowBase = blockIdx.x * 64 + wave * 16;

    int arow = rowBase + l15;
    if (arow >= NP) arow = NP - 1;
    const float* ap = x + (size_t)arow * 128 + quad * 8;
    bf16x8 ahi[4], alo[4];
#pragma unroll
    for (int kt = 0; kt < 4; ++kt) load_split(ap + kt * 32, ahi[kt], alo[kt]);

    f32x4 acc[4];
#pragma unroll
    for (int ct = 0; ct < 4; ++ct) acc[ct] = (f32x4){0.f, 0.f, 0.f, 0.f};

#pragma unroll
    for (int ct = 0; ct < 4; ++ct) {
        int col = ct * 16 + l15;
        const float* bp = Wf + (size_t)col * 128 + quad * 8;
#pragma unroll
        for (int kt = 0; kt < 4; ++kt) {
            bf16x8 bhi, blo;
            load_split(bp + kt * 32, bhi, blo);
            acc[ct] = __builtin_amdgcn_mfma_f32_16x16x32_bf16(ahi[kt], bhi, acc[ct], 0, 0, 0);
            acc[ct] = __builtin_amdgcn_mfma_f32_16x16x32_bf16(ahi[kt], blo, acc[ct], 0, 0, 0);
            acc[ct] = __builtin_amdgcn_mfma_f32_16x16x32_bf16(alo[kt], bhi, acc[ct], 0, 0, 0);
        }
    }

#pragma unroll
    for (int ct = 0; ct < 4; ++ct) {
        int col = ct * 16 + l15;
        float bias = bfp[col];
#pragma unroll
        for (int r = 0; r < 4; ++r) {
            int n = rowBase + quad * 4 + r;
            if (n < NP) xf[(size_t)n * 64 + col] = acc[ct][r] + bias;
        }
    }
}

// per level: x_iou (192 cols, in-register) + Uh_sum/fc_sum -> cell -> h,c (f32 to d_out)
__global__ __launch_bounds__(256) void projcell_kernel(
    const float* __restrict__ x, const float* __restrict__ Wiou,
    const float* __restrict__ biou,
    const float* __restrict__ uh, const float* __restrict__ fcs,
    float* __restrict__ h_all, float* __restrict__ c_all,
    int s0, int s1, int read_sums)
{
    int wave = threadIdx.x >> 6, lane = threadIdx.x & 63;
    int l15 = lane & 15, quad = lane >> 4;
    int rowBase = blockIdx.x * 64 + wave * 16;    // relative to s0

    int arow = s0 + rowBase + l15;
    if (arow >= s1) arow = s1 - 1;
    const float* ap = x + (size_t)arow * 128 + quad * 8;
    bf16x8 ahi[4], alo[4];
#pragma unroll
    for (int kt = 0; kt < 4; ++kt) load_split(ap + kt * 32, ahi[kt], alo[kt]);

    f32x4 acc[12];
#pragma unroll
    for (int ct = 0; ct < 12; ++ct) acc[ct] = (f32x4){0.f, 0.f, 0.f, 0.f};

#pragma unroll
    for (int ct = 0; ct < 12; ++ct) {
        int col = ct * 16 + l15;
        const float* bp = Wiou + (size_t)col * 128 + quad * 8;
#pragma unroll
        for (int kt = 0; kt < 4; ++kt) {
            bf16x8 bhi, blo;
            load_split(bp + kt * 32, bhi, blo);
            acc[ct] = __builtin_amdgcn_mfma_f32_16x16x32_bf16(ahi[kt], bhi, acc[ct], 0, 0, 0);
            acc[ct] = __builtin_amdgcn_mfma_f32_16x16x32_bf16(ahi[kt], blo, acc[ct], 0, 0, 0);
            acc[ct] = __builtin_amdgcn_mfma_f32_16x16x32_bf16(alo[kt], bhi, acc[ct], 0, 0, 0);
        }
    }

#pragma unroll
    for (int g = 0; g < 4; ++g) {
        int j = g * 16 + l15;
        float bi = biou[j], bo = biou[64 + j], bu = biou[128 + j];
#pragma unroll
        for (int r = 0; r < 4; ++r) {
            int n = s0 + rowBase + quad * 4 + r;
            if (n < s1) {
                float iv = acc[g][r] + bi;
                float ov = acc[4 + g][r] + bo;
                float uv = acc[8 + g][r] + bu;
                float ui = 0.f, uo = 0.f, uu = 0.f, fc0 = 0.f;
                if (read_sums) {
                    size_t b = (size_t)n * 192;
                    ui = uh[b + j]; uo = uh[b + 64 + j]; uu = uh[b + 128 + j];
                    fc0 = fcs[(size_t)n * 64 + j];
                }
                float c = sigmoidf_(iv + ui) * tanhf_(uv + uu) + fc0;
                float h = sigmoidf_(ov + uo) * tanhf_(c);
                h_all[(size_t)n * 64 + j] = h;
                c_all[(size_t)n * 64 + j] = c;
            }
        }
    }
}

// -------- edge GEMM: per (level,mid) bin, chunks of 64 edges/block, MFMA, NO atomics.
// tmp[e-ebase][256] = [Uh (192) | hf (64)] per edge, f32.
__global__ __launch_bounds__(256) void edge_gemm_kernel(
    const float* __restrict__ h_all,
    const unsigned short* __restrict__ Upack,
    const int* __restrict__ bin_off, const int* __restrict__ ord,
    float* __restrict__ tmp, int lvl, int ebase, int nbslots)
{
    __shared__ unsigned short sU[32768];   // [hi 16K][lo 16K] frag-packed, 64 KB

    int bin = lvl * 32 + (blockIdx.x & 31);
    int bslot = blockIdx.x >> 5;
    int off = bin_off[bin];
    int cnt = bin_off[bin + 1] - off;
    if (bslot * 64 >= cnt) return;     // block-uniform, before any barrier

    int mid = bin & 31;
    {
        const float4* src = (const float4*)(Upack + (size_t)mid * 32768);
        float4* dst = (float4*)sU;
        for (int i = threadIdx.x; i < 4096; i += 256) dst[i] = src[i];
    }
    __syncthreads();

    int wid = threadIdx.x >> 6, lane = threadIdx.x & 63;
    int l15 = lane & 15, quad = lane >> 4;

    for (int c = bslot; c * 64 < cnt; c += nbslots) {
        int jrow = c * 64 + wid * 16 + l15;
        int jc = (jrow < cnt) ? jrow : cnt - 1;         // pad: duplicate last edge
        int e = ord[off + jc];
        const float* hp = h_all + (size_t)(e + E0) * 64 + quad * 8;
        bf16x8 ahi[2], alo[2];
        load_split(hp, ahi[0], alo[0]);
        load_split(hp + 32, ahi[1], alo[1]);

        f32x4 acc[16];
#pragma unroll
        for (int ct = 0; ct < 16; ++ct) acc[ct] = (f32x4){0.f, 0.f, 0.f, 0.f};

#pragma unroll
        for (int ct = 0; ct < 16; ++ct) {
#pragma unroll
            for (int kt = 0; kt < 2; ++kt) {
                int f = ct * 2 + kt;
                const bf16x8 bhi = *(const bf16x8*)&sU[f * 512 + lane * 8];
                const bf16x8 blo = *(const bf16x8*)&sU[16384 + f * 512 + lane * 8];
                acc[ct] = __builtin_amdgcn_mfma_f32_16x16x32_bf16(ahi[kt], bhi, acc[ct], 0, 0, 0);
                acc[ct] = __builtin_amdgcn_mfma_f32_16x16x32_bf16(ahi[kt], blo, acc[ct], 0, 0, 0);
                acc[ct] = __builtin_amdgcn_mfma_f32_16x16x32_bf16(alo[kt], bhi, acc[ct], 0, 0, 0);
            }
        }

        // epilogue: C row = quad*4+r (within chunk), col = ct*16+l15
        int rowb = c * 64 + wid * 16 + quad * 4;
#pragma unroll
        for (int r = 0; r < 4; ++r) {
            int jr = rowb + r;
            if (jr < cnt) {
                int e2 = ord[off + jr];
                float* op = tmp + (size_t)(e2 - ebase) * 256 + l15;
#pragma unroll
                for (int ct = 0; ct < 16; ++ct) op[ct * 16] = acc[ct][r];
            }
        }
    }
}

// -------- gather: one wave per parent, sum children tmp rows, write uh/fcs once --------
__global__ __launch_bounds__(256) void scatter_kernel(
    const float* __restrict__ tmp, const float* __restrict__ c_all,
    const float* __restrict__ xf,
    const int* __restrict__ childOff, const int* __restrict__ childList,
    float* __restrict__ uh, float* __restrict__ fcs,
    int p0, int p1, int ebase)
{
    int wid = threadIdx.x >> 6, lane = threadIdx.x & 63;
    int p = p0 + blockIdx.x * 4 + wid;
    if (p >= p1) return;
    int c0 = childOff[p], c1 = childOff[p + 1];
    float u0 = 0.f, u1 = 0.f, u2 = 0.f, fc = 0.f;
    float xfv = xf[(size_t)p * 64 + lane];
    for (int ci = c0; ci < c1; ++ci) {
        int e = childList[ci];
        const float* tp = tmp + (size_t)(e - ebase) * 256;
        u0 += tp[lane];
        u1 += tp[64 + lane];
        u2 += tp[128 + lane];
        float hf = tp[192 + lane];
        fc += sigmoidf_(xfv + hf) * c_all[(size_t)(e + E0) * 64 + lane];
    }
    uh[(size_t)p * 192 + lane] = u0;
    uh[(size_t)p * 192 + 64 + lane] = u1;
    uh[(size_t)p * 192 + 128 + lane] = u2;
    fcs[(size_t)p * 64 + lane] = fc;
}

// -------- fallback (ws too small): original per-edge atomic kernel --------
__global__ __launch_bounds__(256) void edge_kernel(
    const float* __restrict__ h_all, const float* __restrict__ c_all,
    const float* __restrict__ xf,
    float* __restrict__ uh, float* __restrict__ fcs,
    const float* __restrict__ Uiou, const float* __restrict__ Ufm,
    const int* __restrict__ edge_dst, const int* __restrict__ mat_id,
    int s0, int s1)
{
    __shared__ float hbuf[4][64];
    __shared__ float cbuf[4][64];
    int wid = threadIdx.x >> 6, lane = threadIdx.x & 63;
    int n = s0 + blockIdx.x * 4 + wid;
    if (n >= s1) return;

    hbuf[wid][lane] = h_all[(size_t)n * 64 + lane];
    cbuf[wid][lane] = c_all[(size_t)n * 64 + lane];

    int e = n - E0;
    int dst = edge_dst[e];
    int mid = mat_id[e];

    bool isf = (lane >= 48);
    int cb = isf ? 4 * (lane - 48) : 4 * lane;
    const float* p = isf ? (Ufm + (size_t)mid * 4096 + cb)
                         : (Uiou + (size_t)mid * 12288 + cb);
    int stride = isf ? 64 : 192;

    float a0 = 0.f, a1 = 0.f, a2 = 0.f, a3 = 0.f;
    for (int k = 0; k < 64; k += 4) {
        float4 hv = *(const float4*)&hbuf[wid][k];
#pragma unroll
        for (int t = 0; t < 4; ++t) {
            float4 u = *(const float4*)p;
            p += stride;
            float hvt = ((const float*)&hv)[t];
            a0 += hvt * u.x; a1 += hvt * u.y; a2 += hvt * u.z; a3 += hvt * u.w;
        }
    }

    if (isf) {
        size_t d = (size_t)dst * 64 + cb;
        float4 cv = *(const float4*)&cbuf[wid][cb];
        atomicAdd(&fcs[d + 0], sigmoidf_(xf[d + 0] + a0) * cv.x);
        atomicAdd(&fcs[d + 1], sigmoidf_(xf[d + 1] + a1) * cv.y);
        atomicAdd(&fcs[d + 2], sigmoidf_(xf[d + 2] + a2) * cv.z);
        atomicAdd(&fcs[d + 3], sigmoidf_(xf[d + 3] + a3) * cv.w);
    } else {
        size_t d = (size_t)dst * 192 + cb;
        atomicAdd(&uh[d + 0], a0);
        atomicAdd(&uh[d + 1], a1);
        atomicAdd(&uh[d + 2], a2);
        atomicAdd(&uh[d + 3], a3);
    }
}

extern "C" void kernel_launch(void* const* d_in, const int* in_sizes, int n_in,
                              void* d_out, int out_size, void* d_ws, size_t ws_size,
                              hipStream_t stream) {
    const float* x      = (const float*)d_in[0];
    // d_in[1] = edge_src == arange(500, 52500) -> unused
    const int* edge_dst = (const int*)d_in[2];
    const int* mat_id   = (const int*)d_in[3];
    const float* Wiou   = (const float*)d_in[4];
    const float* biou   = (const float*)d_in[5];
    const float* Wf     = (const float*)d_in[6];
    const float* bfp    = (const float*)d_in[7];
    const float* Uiou   = (const float*)d_in[8];
    const float* Ufm    = (const float*)d_in[9];

    // ws layout (f32 units unless noted):
    // [uh NP*192][fcs NP*64][xf NP*64][tmp MAXEL*256][Upack 32*32768 ushort]
    // [bin_off 193][ord NEDGE][childOff NP+1][cursor NP][childList NEDGE] (ints)
    float* uh  = (float*)d_ws;
    float* fcs = uh + (size_t)NP * 192;
    float* xf  = fcs + (size_t)NP * 64;
    float* tmp = xf + (size_t)NP * 64;
    unsigned short* Upack = (unsigned short*)(tmp + (size_t)MAXEL * 256);
    int* bin_off   = (int*)(Upack + (size_t)32 * 32768);
    int* ord       = bin_off + 193;
    int* childOff  = ord + NEDGE;
    int* cursor    = childOff + NP + 1;
    int* childList = cursor + NP;
    size_t need = (size_t)((char*)(childList + NEDGE) - (char*)d_ws);
    int grouped = (ws_size >= need) ? 1 : 0;

    float* out_h = (float*)d_out;            // f32 output: h then c
    float* out_c = out_h + (size_t)NN * 64;

    static const int noff[7] = {0, 500, 2500, 8500, 20500, 36500, 52500};

    if (grouped) {
        // setup (once per replay, all idempotent): mid-bins, dst-CSR, packed U
        zero_kernel<<<(NP / 4 + 255) / 256, 256, 0, stream>>>((float*)cursor, NP / 4); // NP%4==0
        bin_kernel<<<1, 1024, 0, stream>>>(mat_id, bin_off, ord);
        hist_kernel<<<(NEDGE + 255) / 256, 256, 0, stream>>>(edge_dst, cursor);
        scan_kernel<<<1, 1024, 0, stream>>>(cursor, childOff);
        fill_kernel<<<(NEDGE + 255) / 256, 256, 0, stream>>>(edge_dst, cursor, childList);
        upack_kernel<<<32, 256, 0, stream>>>(Uiou, Ufm, Upack);
    } else {
        int n4 = (int)((size_t)NP * 256 / 4);
        zero_kernel<<<(n4 + 255) / 256, 256, 0, stream>>>(uh, n4);
    }

    xfproj_kernel<<<(NP + 63) / 64, 256, 0, stream>>>(x, Wf, bfp, xf);

    for (int l = 5; l >= 0; --l) {
        int s0 = noff[l], s1 = noff[l + 1], nl = s1 - s0;
        projcell_kernel<<<(nl + 63) / 64, 256, 0, stream>>>(
            x, Wiou, biou, uh, fcs, out_h, out_c, s0, s1, (l != 5) ? 1 : 0);
        if (l >= 1) {
            if (grouped) {
                int el = nl;                    // one edge per level-l node
                int ebase = s0 - E0;
                int nbs = (el + 2047) / 2048;   // chunk slots per bin
                edge_gemm_kernel<<<32 * nbs, 256, 0, stream>>>(
                    out_h, Upack, bin_off, ord, tmp, l - 1, ebase, nbs);
                int p0 = noff[l - 1], p1 = s0;
                scatter_kernel<<<(p1 - p0 + 3) / 4, 256, 0, stream>>>(
                    tmp, out_c, xf, childOff, childList, uh, fcs, p0, p1, ebase);
            } else {
                edge_kernel<<<(nl + 3) / 4, 256, 0, stream>>>(
                    out_h, out_c, xf, uh, fcs, Uiou, Ufm, edge_dst, mat_id, s0, s1);
            }
        }
    }
}

// Round 3
// 415.168 us; speedup vs baseline: 2.4515x; 1.1765x over previous
//
#include <hip/hip_runtime.h>

#define NN 52500
#define NP 36500            // nodes with children (levels 0..4) = parents
#define E0 500              // edge e corresponds to src node n = e + 500
#define NEDGE 52000
#define NBINS 160           // 5 edge-levels x 32 matrices
#define MAXEL 16000         // max edges in one level
#define NSB 143             // scan blocks = ceil(NP/256)

__device__ __forceinline__ float sigmoidf_(float x) { return 1.f / (1.f + __expf(-x)); }
__device__ __forceinline__ float tanhf_(float x) {
    float e = __expf(-2.f * fabsf(x));
    return copysignf((1.f - e) / (1.f + e), x);
}

typedef __attribute__((ext_vector_type(8))) short bf16x8;
typedef __attribute__((ext_vector_type(4))) float f32x4;

__device__ __forceinline__ unsigned short f2bf_rne(float f) {
    unsigned int u = __float_as_uint(f);
    u += 0x7FFF + ((u >> 16) & 1);
    return (unsigned short)(u >> 16);
}

// load 8 consecutive f32, split each into bf16 hi + bf16 lo (compensated precision ~2^-17)
__device__ __forceinline__ void load_split(const float* p, bf16x8& hi, bf16x8& lo) {
    float4 a = *(const float4*)p;
    float4 b = *(const float4*)(p + 4);
    float v[8] = {a.x, a.y, a.z, a.w, b.x, b.y, b.z, b.w};
#pragma unroll
    for (int j = 0; j < 8; ++j) {
        unsigned short hu = f2bf_rne(v[j]);
        float hf = __uint_as_float((unsigned int)hu << 16);
        hi[j] = (short)hu;
        lo[j] = (short)f2bf_rne(v[j] - hf);
    }
}

__global__ __launch_bounds__(256) void zero_kernel(float* __restrict__ p, int n4) {
    int i = blockIdx.x * 256 + threadIdx.x;
    if (i < n4) ((float4*)p)[i] = (float4){0.f, 0.f, 0.f, 0.f};
}

// -------- one-time edge binning by (level, matrix_id): 160 bins, single block --------
__global__ __launch_bounds__(1024) void bin_kernel(const int* __restrict__ mat_id,
                                                   int* __restrict__ bin_off,
                                                   int* __restrict__ ord) {
    __shared__ int cnt[NBINS];
    __shared__ int coff[NBINS + 1];
    for (int i = threadIdx.x; i < NBINS; i += 1024) cnt[i] = 0;
    __syncthreads();
    for (int e = threadIdx.x; e < NEDGE; e += 1024) {
        int L = (e >= 2000) + (e >= 8000) + (e >= 20000) + (e >= 36000);
        atomicAdd(&cnt[L * 32 + mat_id[e]], 1);
    }
    __syncthreads();
    if (threadIdx.x == 0) {
        int s = 0;
        for (int i = 0; i < NBINS; ++i) { coff[i] = s; s += cnt[i]; }
        coff[NBINS] = s;
    }
    __syncthreads();
    for (int i = threadIdx.x; i <= NBINS; i += 1024) bin_off[i] = coff[i];
    for (int i = threadIdx.x; i < NBINS; i += 1024) cnt[i] = coff[i];   // reuse as cursor
    __syncthreads();
    for (int e = threadIdx.x; e < NEDGE; e += 1024) {
        int L = (e >= 2000) + (e >= 8000) + (e >= 20000) + (e >= 36000);
        int pos = atomicAdd(&cnt[L * 32 + mat_id[e]], 1);
        ord[pos] = e;
    }
}

// -------- CSR-by-dst build: hist -> 3-phase scan -> fill (once per run) --------
__global__ __launch_bounds__(256) void hist_kernel(const int* __restrict__ edge_dst,
                                                   int* __restrict__ cnt) {
    int e = blockIdx.x * 256 + threadIdx.x;
    if (e < NEDGE) atomicAdd(&cnt[edge_dst[e]], 1);
}

// phase 1: per-block scan of counts -> in-block exclusive prefix + per-block sum
__global__ __launch_bounds__(256) void scan1_kernel(const int* __restrict__ cnt,
                                                    int* __restrict__ off,
                                                    int* __restrict__ bsum) {
    __shared__ int s[256];
    int t = threadIdx.x;
    int i = blockIdx.x * 256 + t;
    int v = (i < NP) ? cnt[i] : 0;
    s[t] = v;
    __syncthreads();
#pragma unroll
    for (int d = 1; d < 256; d <<= 1) {
        int u = (t >= d) ? s[t - d] : 0;
        __syncthreads();
        s[t] += u;
        __syncthreads();
    }
    if (i < NP) off[i] = s[t] - v;          // exclusive within block
    if (t == 255) bsum[blockIdx.x] = s[255];
}

// phase 2: exclusive scan of NSB block sums (single tiny block)
__global__ __launch_bounds__(256) void scan2_kernel(int* __restrict__ bsum) {
    __shared__ int s[256];
    int t = threadIdx.x;
    int v = (t < NSB) ? bsum[t] : 0;
    s[t] = v;
    __syncthreads();
#pragma unroll
    for (int d = 1; d < 256; d <<= 1) {
        int u = (t >= d) ? s[t - d] : 0;
        __syncthreads();
        s[t] += u;
        __syncthreads();
    }
    if (t < NSB) bsum[t] = s[t] - v;        // exclusive
}

// phase 3: add block base, finalize childOff, init cursor
__global__ __launch_bounds__(256) void scan3_kernel(int* __restrict__ off,
                                                    const int* __restrict__ bsum,
                                                    int* __restrict__ cursor) {
    int i = blockIdx.x * 256 + threadIdx.x;
    if (i < NP) {
        int o = off[i] + bsum[blockIdx.x];
        off[i] = o;
        cursor[i] = o;
    }
    if (i == 0) off[NP] = NEDGE;            // total children == total edges
}

__global__ __launch_bounds__(256) void fill_kernel(const int* __restrict__ edge_dst,
                                                   int* __restrict__ cursor,
                                                   int* __restrict__ childList) {
    int e = blockIdx.x * 256 + threadIdx.x;
    if (e < NEDGE) {
        int pos = atomicAdd(&cursor[edge_dst[e]], 1);
        childList[pos] = e;
    }
}

// -------- one-time U pack: [32 mids][hi 16K | lo 16K] bf16 MFMA-B fragments --------
// frag f = ct*2+kt (ct 0..15, kt 0..1); elem(lane,j) = U[kt*32+(lane>>4)*8+j][ct*16+(lane&15)]
// cols 0..191 = U_iou, 192..255 = U_f
__global__ __launch_bounds__(256) void upack_kernel(
    const float* __restrict__ Uiou, const float* __restrict__ Ufm,
    unsigned short* __restrict__ Upack)
{
    int mid = blockIdx.x;
    unsigned short* dhi = Upack + (size_t)mid * 32768;
    unsigned short* dlo = dhi + 16384;
    for (int p0 = threadIdx.x * 8; p0 < 16384; p0 += 2048) {
        int f = p0 >> 9;
        int lane = (p0 >> 3) & 63;
        int kt = f & 1, ct = f >> 1;
        int kbase = kt * 32 + (lane >> 4) * 8;
        int col = ct * 16 + (lane & 15);
#pragma unroll
        for (int j = 0; j < 8; ++j) {
            int k = kbase + j;
            float v = (col < 192) ? Uiou[(size_t)mid * 12288 + k * 192 + col]
                                  : Ufm[(size_t)mid * 4096 + k * 64 + (col - 192)];
            unsigned short hu = f2bf_rne(v);
            float hf = __uint_as_float((unsigned int)hu << 16);
            dhi[p0 + j] = hu;
            dlo[p0 + j] = f2bf_rne(v - hf);
        }
    }
}

// x_f = x @ W_f^T + b_f for nodes 0..NP-1, f32 out, compensated bf16 MFMA
__global__ __launch_bounds__(256) void xfproj_kernel(
    const float* __restrict__ x, const float* __restrict__ Wf,
    const float* __restrict__ bfp, float* __restrict__ xf)
{
    int wave = threadIdx.x >> 6, lane = threadIdx.x & 63;
    int l15 = lane & 15, quad = lane >> 4;
    int rowBase = blockIdx.x * 64 + wave * 16;

    int arow = rowBase + l15;
    if (arow >= NP) arow = NP - 1;
    const float* ap = x + (size_t)arow * 128 + quad * 8;
    bf16x8 ahi[4], alo[4];
#pragma unroll
    for (int kt = 0; kt < 4; ++kt) load_split(ap + kt * 32, ahi[kt], alo[kt]);

    f32x4 acc[4];
#pragma unroll
    for (int ct = 0; ct < 4; ++ct) acc[ct] = (f32x4){0.f, 0.f, 0.f, 0.f};

#pragma unroll
    for (int ct = 0; ct < 4; ++ct) {
        int col = ct * 16 + l15;
        const float* bp = Wf + (size_t)col * 128 + quad * 8;
#pragma unroll
        for (int kt = 0; kt < 4; ++kt) {
            bf16x8 bhi, blo;
            load_split(bp + kt * 32, bhi, blo);
            acc[ct] = __builtin_amdgcn_mfma_f32_16x16x32_bf16(ahi[kt], bhi, acc[ct], 0, 0, 0);
            acc[ct] = __builtin_amdgcn_mfma_f32_16x16x32_bf16(ahi[kt], blo, acc[ct], 0, 0, 0);
            acc[ct] = __builtin_amdgcn_mfma_f32_16x16x32_bf16(alo[kt], bhi, acc[ct], 0, 0, 0);
        }
    }

#pragma unroll
    for (int ct = 0; ct < 4; ++ct) {
        int col = ct * 16 + l15;
        float bias = bfp[col];
#pragma unroll
        for (int r = 0; r < 4; ++r) {
            int n = rowBase + quad * 4 + r;
            if (n < NP) xf[(size_t)n * 64 + col] = acc[ct][r] + bias;
        }
    }
}

// per level: x_iou (192 cols, in-register) + Uh_sum/fc_sum -> cell -> h,c (f32 to d_out)
__global__ __launch_bounds__(256) void projcell_kernel(
    const float* __restrict__ x, const float* __restrict__ Wiou,
    const float* __restrict__ biou,
    const float* __restrict__ uh, const float* __restrict__ fcs,
    float* __restrict__ h_all, float* __restrict__ c_all,
    int s0, int s1, int read_sums)
{
    int wave = threadIdx.x >> 6, lane = threadIdx.x & 63;
    int l15 = lane & 15, quad = lane >> 4;
    int rowBase = blockIdx.x * 64 + wave * 16;    // relative to s0

    int arow = s0 + rowBase + l15;
    if (arow >= s1) arow = s1 - 1;
    const float* ap = x + (size_t)arow * 128 + quad * 8;
    bf16x8 ahi[4], alo[4];
#pragma unroll
    for (int kt = 0; kt < 4; ++kt) load_split(ap + kt * 32, ahi[kt], alo[kt]);

    f32x4 acc[12];
#pragma unroll
    for (int ct = 0; ct < 12; ++ct) acc[ct] = (f32x4){0.f, 0.f, 0.f, 0.f};

#pragma unroll
    for (int ct = 0; ct < 12; ++ct) {
        int col = ct * 16 + l15;
        const float* bp = Wiou + (size_t)col * 128 + quad * 8;
#pragma unroll
        for (int kt = 0; kt < 4; ++kt) {
            bf16x8 bhi, blo;
            load_split(bp + kt * 32, bhi, blo);
            acc[ct] = __builtin_amdgcn_mfma_f32_16x16x32_bf16(ahi[kt], bhi, acc[ct], 0, 0, 0);
            acc[ct] = __builtin_amdgcn_mfma_f32_16x16x32_bf16(ahi[kt], blo, acc[ct], 0, 0, 0);
            acc[ct] = __builtin_amdgcn_mfma_f32_16x16x32_bf16(alo[kt], bhi, acc[ct], 0, 0, 0);
        }
    }

#pragma unroll
    for (int g = 0; g < 4; ++g) {
        int j = g * 16 + l15;
        float bi = biou[j], bo = biou[64 + j], bu = biou[128 + j];
#pragma unroll
        for (int r = 0; r < 4; ++r) {
            int n = s0 + rowBase + quad * 4 + r;
            if (n < s1) {
                float iv = acc[g][r] + bi;
                float ov = acc[4 + g][r] + bo;
                float uv = acc[8 + g][r] + bu;
                float ui = 0.f, uo = 0.f, uu = 0.f, fc0 = 0.f;
                if (read_sums) {
                    size_t b = (size_t)n * 192;
                    ui = uh[b + j]; uo = uh[b + 64 + j]; uu = uh[b + 128 + j];
                    fc0 = fcs[(size_t)n * 64 + j];
                }
                float c = sigmoidf_(iv + ui) * tanhf_(uv + uu) + fc0;
                float h = sigmoidf_(ov + uo) * tanhf_(c);
                h_all[(size_t)n * 64 + j] = h;
                c_all[(size_t)n * 64 + j] = c;
            }
        }
    }
}

// -------- edge GEMM: per (level,mid) bin, chunks of 64 edges/block, MFMA, NO atomics.
// tmp[e-ebase][256] = [Uh (192) | hf (64)] per edge, f32.
__global__ __launch_bounds__(256) void edge_gemm_kernel(
    const float* __restrict__ h_all,
    const unsigned short* __restrict__ Upack,
    const int* __restrict__ bin_off, const int* __restrict__ ord,
    float* __restrict__ tmp, int lvl, int ebase, int nbslots)
{
    __shared__ unsigned short sU[32768];   // [hi 16K][lo 16K] frag-packed, 64 KB

    int bin = lvl * 32 + (blockIdx.x & 31);
    int bslot = blockIdx.x >> 5;
    int off = bin_off[bin];
    int cnt = bin_off[bin + 1] - off;
    if (bslot * 64 >= cnt) return;     // block-uniform, before any barrier

    int mid = bin & 31;
    {
        const float4* src = (const float4*)(Upack + (size_t)mid * 32768);
        float4* dst = (float4*)sU;
        for (int i = threadIdx.x; i < 4096; i += 256) dst[i] = src[i];
    }
    __syncthreads();

    int wid = threadIdx.x >> 6, lane = threadIdx.x & 63;
    int l15 = lane & 15, quad = lane >> 4;

    for (int c = bslot; c * 64 < cnt; c += nbslots) {
        int jrow = c * 64 + wid * 16 + l15;
        int jc = (jrow < cnt) ? jrow : cnt - 1;         // pad: duplicate last edge
        int e = ord[off + jc];
        const float* hp = h_all + (size_t)(e + E0) * 64 + quad * 8;
        bf16x8 ahi[2], alo[2];
        load_split(hp, ahi[0], alo[0]);
        load_split(hp + 32, ahi[1], alo[1]);

        f32x4 acc[16];
#pragma unroll
        for (int ct = 0; ct < 16; ++ct) acc[ct] = (f32x4){0.f, 0.f, 0.f, 0.f};

#pragma unroll
        for (int ct = 0; ct < 16; ++ct) {
#pragma unroll
            for (int kt = 0; kt < 2; ++kt) {
                int f = ct * 2 + kt;
                const bf16x8 bhi = *(const bf16x8*)&sU[f * 512 + lane * 8];
                const bf16x8 blo = *(const bf16x8*)&sU[16384 + f * 512 + lane * 8];
                acc[ct] = __builtin_amdgcn_mfma_f32_16x16x32_bf16(ahi[kt], bhi, acc[ct], 0, 0, 0);
                acc[ct] = __builtin_amdgcn_mfma_f32_16x16x32_bf16(ahi[kt], blo, acc[ct], 0, 0, 0);
                acc[ct] = __builtin_amdgcn_mfma_f32_16x16x32_bf16(alo[kt], bhi, acc[ct], 0, 0, 0);
            }
        }

        // epilogue: C row = quad*4+r (within chunk), col = ct*16+l15
        int rowb = c * 64 + wid * 16 + quad * 4;
#pragma unroll
        for (int r = 0; r < 4; ++r) {
            int jr = rowb + r;
            if (jr < cnt) {
                int e2 = ord[off + jr];
                float* op = tmp + (size_t)(e2 - ebase) * 256 + l15;
#pragma unroll
                for (int ct = 0; ct < 16; ++ct) op[ct * 16] = acc[ct][r];
            }
        }
    }
}

// -------- gather: one wave per parent, sum children tmp rows, write uh/fcs once --------
__global__ __launch_bounds__(256) void scatter_kernel(
    const float* __restrict__ tmp, const float* __restrict__ c_all,
    const float* __restrict__ xf,
    const int* __restrict__ childOff, const int* __restrict__ childList,
    float* __restrict__ uh, float* __restrict__ fcs,
    int p0, int p1, int ebase)
{
    int wid = threadIdx.x >> 6, lane = threadIdx.x & 63;
    int p = p0 + blockIdx.x * 4 + wid;
    if (p >= p1) return;
    int c0 = childOff[p], c1 = childOff[p + 1];
    float u0 = 0.f, u1 = 0.f, u2 = 0.f, fc = 0.f;
    float xfv = xf[(size_t)p * 64 + lane];
    for (int ci = c0; ci < c1; ++ci) {
        int e = childList[ci];
        const float* tp = tmp + (size_t)(e - ebase) * 256;
        u0 += tp[lane];
        u1 += tp[64 + lane];
        u2 += tp[128 + lane];
        float hf = tp[192 + lane];
        fc += sigmoidf_(xfv + hf) * c_all[(size_t)(e + E0) * 64 + lane];
    }
    uh[(size_t)p * 192 + lane] = u0;
    uh[(size_t)p * 192 + 64 + lane] = u1;
    uh[(size_t)p * 192 + 128 + lane] = u2;
    fcs[(size_t)p * 64 + lane] = fc;
}

// -------- fallback (ws too small): original per-edge atomic kernel --------
__global__ __launch_bounds__(256) void edge_kernel(
    const float* __restrict__ h_all, const float* __restrict__ c_all,
    const float* __restrict__ xf,
    float* __restrict__ uh, float* __restrict__ fcs,
    const float* __restrict__ Uiou, const float* __restrict__ Ufm,
    const int* __restrict__ edge_dst, const int* __restrict__ mat_id,
    int s0, int s1)
{
    __shared__ float hbuf[4][64];
    __shared__ float cbuf[4][64];
    int wid = threadIdx.x >> 6, lane = threadIdx.x & 63;
    int n = s0 + blockIdx.x * 4 + wid;
    if (n >= s1) return;

    hbuf[wid][lane] = h_all[(size_t)n * 64 + lane];
    cbuf[wid][lane] = c_all[(size_t)n * 64 + lane];

    int e = n - E0;
    int dst = edge_dst[e];
    int mid = mat_id[e];

    bool isf = (lane >= 48);
    int cb = isf ? 4 * (lane - 48) : 4 * lane;
    const float* p = isf ? (Ufm + (size_t)mid * 4096 + cb)
                         : (Uiou + (size_t)mid * 12288 + cb);
    int stride = isf ? 64 : 192;

    float a0 = 0.f, a1 = 0.f, a2 = 0.f, a3 = 0.f;
    for (int k = 0; k < 64; k += 4) {
        float4 hv = *(const float4*)&hbuf[wid][k];
#pragma unroll
        for (int t = 0; t < 4; ++t) {
            float4 u = *(const float4*)p;
            p += stride;
            float hvt = ((const float*)&hv)[t];
            a0 += hvt * u.x; a1 += hvt * u.y; a2 += hvt * u.z; a3 += hvt * u.w;
        }
    }

    if (isf) {
        size_t d = (size_t)dst * 64 + cb;
        float4 cv = *(const float4*)&cbuf[wid][cb];
        atomicAdd(&fcs[d + 0], sigmoidf_(xf[d + 0] + a0) * cv.x);
        atomicAdd(&fcs[d + 1], sigmoidf_(xf[d + 1] + a1) * cv.y);
        atomicAdd(&fcs[d + 2], sigmoidf_(xf[d + 2] + a2) * cv.z);
        atomicAdd(&fcs[d + 3], sigmoidf_(xf[d + 3] + a3) * cv.w);
    } else {
        size_t d = (size_t)dst * 192 + cb;
        atomicAdd(&uh[d + 0], a0);
        atomicAdd(&uh[d + 1], a1);
        atomicAdd(&uh[d + 2], a2);
        atomicAdd(&uh[d + 3], a3);
    }
}

extern "C" void kernel_launch(void* const* d_in, const int* in_sizes, int n_in,
                              void* d_out, int out_size, void* d_ws, size_t ws_size,
                              hipStream_t stream) {
    const float* x      = (const float*)d_in[0];
    // d_in[1] = edge_src == arange(500, 52500) -> unused
    const int* edge_dst = (const int*)d_in[2];
    const int* mat_id   = (const int*)d_in[3];
    const float* Wiou   = (const float*)d_in[4];
    const float* biou   = (const float*)d_in[5];
    const float* Wf     = (const float*)d_in[6];
    const float* bfp    = (const float*)d_in[7];
    const float* Uiou   = (const float*)d_in[8];
    const float* Ufm    = (const float*)d_in[9];

    // ws layout (f32 units unless noted):
    // [uh NP*192][fcs NP*64][xf NP*64][tmp MAXEL*256][Upack 32*32768 ushort]
    // [bin_off 193][ord NEDGE][childOff NP+1][cursor NP][childList NEDGE][bsum NSB] (ints)
    float* uh  = (float*)d_ws;
    float* fcs = uh + (size_t)NP * 192;
    float* xf  = fcs + (size_t)NP * 64;
    float* tmp = xf + (size_t)NP * 64;
    unsigned short* Upack = (unsigned short*)(tmp + (size_t)MAXEL * 256);
    int* bin_off   = (int*)(Upack + (size_t)32 * 32768);
    int* ord       = bin_off + 193;
    int* childOff  = ord + NEDGE;
    int* cursor    = childOff + NP + 1;
    int* childList = cursor + NP;
    int* bsum      = childList + NEDGE;
    size_t need = (size_t)((char*)(bsum + NSB) - (char*)d_ws);
    int grouped = (ws_size >= need) ? 1 : 0;

    float* out_h = (float*)d_out;            // f32 output: h then c
    float* out_c = out_h + (size_t)NN * 64;

    static const int noff[7] = {0, 500, 2500, 8500, 20500, 36500, 52500};

    if (grouped) {
        // setup (once per replay, all idempotent): mid-bins, dst-CSR, packed U
        zero_kernel<<<(NP / 4 + 255) / 256, 256, 0, stream>>>((float*)cursor, NP / 4); // NP%4==0
        bin_kernel<<<1, 1024, 0, stream>>>(mat_id, bin_off, ord);
        hist_kernel<<<(NEDGE + 255) / 256, 256, 0, stream>>>(edge_dst, cursor);
        scan1_kernel<<<NSB, 256, 0, stream>>>(cursor, childOff, bsum);
        scan2_kernel<<<1, 256, 0, stream>>>(bsum);
        scan3_kernel<<<NSB, 256, 0, stream>>>(childOff, bsum, cursor);
        fill_kernel<<<(NEDGE + 255) / 256, 256, 0, stream>>>(edge_dst, cursor, childList);
        upack_kernel<<<32, 256, 0, stream>>>(Uiou, Ufm, Upack);
    } else {
        int n4 = (int)((size_t)NP * 256 / 4);
        zero_kernel<<<(n4 + 255) / 256, 256, 0, stream>>>(uh, n4);
    }

    xfproj_kernel<<<(NP + 63) / 64, 256, 0, stream>>>(x, Wf, bfp, xf);

    for (int l = 5; l >= 0; --l) {
        int s0 = noff[l], s1 = noff[l + 1], nl = s1 - s0;
        projcell_kernel<<<(nl + 63) / 64, 256, 0, stream>>>(
            x, Wiou, biou, uh, fcs, out_h, out_c, s0, s1, (l != 5) ? 1 : 0);
        if (l >= 1) {
            if (grouped) {
                int el = nl;                    // one edge per level-l node
                int ebase = s0 - E0;
                int nbs = (el + 2047) / 2048;   // chunk slots per bin
                edge_gemm_kernel<<<32 * nbs, 256, 0, stream>>>(
                    out_h, Upack, bin_off, ord, tmp, l - 1, ebase, nbs);
                int p0 = noff[l - 1], p1 = s0;
                scatter_kernel<<<(p1 - p0 + 3) / 4, 256, 0, stream>>>(
                    tmp, out_c, xf, childOff, childList, uh, fcs, p0, p1, ebase);
            } else {
                edge_kernel<<<(nl + 3) / 4, 256, 0, stream>>>(
                    out_h, out_c, xf, uh, fcs, Uiou, Ufm, edge_dst, mat_id, s0, s1);
            }
        }
    }
}

// Round 4
// 393.469 us; speedup vs baseline: 2.5866x; 1.0551x over previous
//
#include <hip/hip_runtime.h>

#define NN 52500
#define NP 36500            // nodes with children (levels 0..4) = parents
#define E0 500              // edge e corresponds to src node n = e + 500
#define NEDGE 52000
#define NBINS 160           // 5 edge-levels x 32 matrices
#define MAXEL 16000         // max edges in one level
#define NSB 143             // scan blocks = ceil(NP/256)

__device__ __forceinline__ float sigmoidf_(float x) { return 1.f / (1.f + __expf(-x)); }
__device__ __forceinline__ float tanhf_(float x) {
    float e = __expf(-2.f * fabsf(x));
    return copysignf((1.f - e) / (1.f + e), x);
}

typedef __attribute__((ext_vector_type(8))) short bf16x8;
typedef __attribute__((ext_vector_type(4))) float f32x4;

__device__ __forceinline__ unsigned short f2bf_rne(float f) {
    unsigned int u = __float_as_uint(f);
    u += 0x7FFF + ((u >> 16) & 1);
    return (unsigned short)(u >> 16);
}

// load 8 consecutive f32, split each into bf16 hi + bf16 lo (compensated precision ~2^-17)
__device__ __forceinline__ void load_split(const float* p, bf16x8& hi, bf16x8& lo) {
    float4 a = *(const float4*)p;
    float4 b = *(const float4*)(p + 4);
    float v[8] = {a.x, a.y, a.z, a.w, b.x, b.y, b.z, b.w};
#pragma unroll
    for (int j = 0; j < 8; ++j) {
        unsigned short hu = f2bf_rne(v[j]);
        float hf = __uint_as_float((unsigned int)hu << 16);
        hi[j] = (short)hu;
        lo[j] = (short)f2bf_rne(v[j] - hf);
    }
}

__global__ __launch_bounds__(256) void zero_kernel(float* __restrict__ p, int n4) {
    int i = blockIdx.x * 256 + threadIdx.x;
    if (i < n4) ((float4*)p)[i] = (float4){0.f, 0.f, 0.f, 0.f};
}

// -------- CSR hist (by dst) + bin hist (by level,mid), one parallel pass --------
__global__ __launch_bounds__(256) void hist_kernel(const int* __restrict__ edge_dst,
                                                   const int* __restrict__ mat_id,
                                                   int* __restrict__ cnt,
                                                   int* __restrict__ bincnt /*stride 16*/) {
    int e = blockIdx.x * 256 + threadIdx.x;
    if (e < NEDGE) {
        atomicAdd(&cnt[edge_dst[e]], 1);
        int L = (e >= 2000) + (e >= 8000) + (e >= 20000) + (e >= 36000);
        atomicAdd(&bincnt[(L * 32 + mat_id[e]) * 16], 1);
    }
}

// phase 1: per-block scan of counts -> in-block exclusive prefix + per-block sum
__global__ __launch_bounds__(256) void scan1_kernel(const int* __restrict__ cnt,
                                                    int* __restrict__ off,
                                                    int* __restrict__ bsum) {
    __shared__ int s[256];
    int t = threadIdx.x;
    int i = blockIdx.x * 256 + t;
    int v = (i < NP) ? cnt[i] : 0;
    s[t] = v;
    __syncthreads();
#pragma unroll
    for (int d = 1; d < 256; d <<= 1) {
        int u = (t >= d) ? s[t - d] : 0;
        __syncthreads();
        s[t] += u;
        __syncthreads();
    }
    if (i < NP) off[i] = s[t] - v;          // exclusive within block
    if (t == 255) bsum[blockIdx.x] = s[255];
}

// phase 2: exclusive scan of NSB block sums AND exclusive scan of 160 bin counts
__global__ __launch_bounds__(256) void scan2_kernel(int* __restrict__ bsum,
                                                    const int* __restrict__ bincnt,
                                                    int* __restrict__ bin_off,
                                                    int* __restrict__ bincur) {
    __shared__ int s[256];
    __shared__ int b[256];
    int t = threadIdx.x;
    int v = (t < NSB) ? bsum[t] : 0;
    int bv = (t < NBINS) ? bincnt[t * 16] : 0;
    s[t] = v;
    b[t] = bv;
    __syncthreads();
#pragma unroll
    for (int d = 1; d < 256; d <<= 1) {
        int u  = (t >= d) ? s[t - d] : 0;
        int ub = (t >= d) ? b[t - d] : 0;
        __syncthreads();
        s[t] += u;
        b[t] += ub;
        __syncthreads();
    }
    if (t < NSB) bsum[t] = s[t] - v;        // exclusive
    if (t < NBINS) {
        int o = b[t] - bv;                  // exclusive
        bin_off[t] = o;
        bincur[t * 16] = o;
    }
    if (t == 0) bin_off[NBINS] = NEDGE;
}

// phase 3: add block base, finalize childOff, init cursor
__global__ __launch_bounds__(256) void scan3_kernel(int* __restrict__ off,
                                                    const int* __restrict__ bsum,
                                                    int* __restrict__ cursor) {
    int i = blockIdx.x * 256 + threadIdx.x;
    if (i < NP) {
        int o = off[i] + bsum[blockIdx.x];
        off[i] = o;
        cursor[i] = o;
    }
    if (i == 0) off[NP] = NEDGE;            // total children == total edges
}

__global__ __launch_bounds__(256) void fill_kernel(const int* __restrict__ edge_dst,
                                                   int* __restrict__ cursor,
                                                   int* __restrict__ childList) {
    int e = blockIdx.x * 256 + threadIdx.x;
    if (e < NEDGE) {
        int pos = atomicAdd(&cursor[edge_dst[e]], 1);
        childList[pos] = e;
    }
}

// parallel ord fill (order within a bin is irrelevant downstream)
__global__ __launch_bounds__(256) void binfill_kernel(const int* __restrict__ mat_id,
                                                      int* __restrict__ bincur,
                                                      int* __restrict__ ord) {
    int e = blockIdx.x * 256 + threadIdx.x;
    if (e < NEDGE) {
        int L = (e >= 2000) + (e >= 8000) + (e >= 20000) + (e >= 36000);
        int pos = atomicAdd(&bincur[(L * 32 + mat_id[e]) * 16], 1);
        ord[pos] = e;
    }
}

// -------- one-time U pack: [32 mids][hi 16K | lo 16K] bf16 MFMA-B fragments --------
// frag f = ct*2+kt (ct 0..15, kt 0..1); elem(lane,j) = U[kt*32+(lane>>4)*8+j][ct*16+(lane&15)]
// cols 0..191 = U_iou, 192..255 = U_f
__global__ __launch_bounds__(256) void upack_kernel(
    const float* __restrict__ Uiou, const float* __restrict__ Ufm,
    unsigned short* __restrict__ Upack)
{
    int mid = blockIdx.x;
    unsigned short* dhi = Upack + (size_t)mid * 32768;
    unsigned short* dlo = dhi + 16384;
    for (int p0 = threadIdx.x * 8; p0 < 16384; p0 += 2048) {
        int f = p0 >> 9;
        int lane = (p0 >> 3) & 63;
        int kt = f & 1, ct = f >> 1;
        int kbase = kt * 32 + (lane >> 4) * 8;
        int col = ct * 16 + (lane & 15);
#pragma unroll
        for (int j = 0; j < 8; ++j) {
            int k = kbase + j;
            float v = (col < 192) ? Uiou[(size_t)mid * 12288 + k * 192 + col]
                                  : Ufm[(size_t)mid * 4096 + k * 64 + (col - 192)];
            unsigned short hu = f2bf_rne(v);
            float hf = __uint_as_float((unsigned int)hu << 16);
            dhi[p0 + j] = hu;
            dlo[p0 + j] = f2bf_rne(v - hf);
        }
    }
}

// -------- one-time W pack: Wiou (48 frags) + Wf (16 frags), hi/lo, B-fragment layout --
// frag f=ct*4+kt; elem(lane,j) = W[ct*16+(lane&15)][kt*32+(lane>>4)*8+j]
// layout (ushort): [IOU_HI 0][IOU_LO 24576][F_HI 49152][F_LO 57344], total 65536
__global__ __launch_bounds__(256) void wpack_kernel(
    const float* __restrict__ Wiou, const float* __restrict__ Wf,
    unsigned short* __restrict__ Wpk)
{
    int p = blockIdx.x * 256 + threadIdx.x;    // 0..32767
    if (p >= 32768) return;
    int f = p >> 9, lane = (p >> 3) & 63, j = p & 7;
    int l15 = lane & 15, quad = lane >> 4;
    float v;
    int hioff, fi;
    if (f < 48) {
        int ct = f >> 2, kt = f & 3;
        v = Wiou[(size_t)(ct * 16 + l15) * 128 + kt * 32 + quad * 8 + j];
        hioff = 0; fi = f;
    } else {
        int ff = f - 48;
        int ct = ff >> 2, kt = ff & 3;
        v = Wf[(size_t)(ct * 16 + l15) * 128 + kt * 32 + quad * 8 + j];
        hioff = 49152; fi = ff;
    }
    unsigned short hu = f2bf_rne(v);
    float hf = __uint_as_float((unsigned int)hu << 16);
    Wpk[hioff + fi * 512 + lane * 8 + j] = hu;
    Wpk[hioff + 24576 / 3 * 0 + (f < 48 ? 24576 : 8192) + fi * 512 + lane * 8 + j] = f2bf_rne(v - hf);
}

// x_f = x @ W_f^T + b_f for nodes 0..NP-1, f32 out, compensated bf16 MFMA
__global__ __launch_bounds__(256) void xfproj_kernel(
    const float* __restrict__ x, const unsigned short* __restrict__ Wpk,
    const float* __restrict__ bfp, float* __restrict__ xf)
{
    int wave = threadIdx.x >> 6, lane = threadIdx.x & 63;
    int l15 = lane & 15, quad = lane >> 4;
    int rowBase = blockIdx.x * 64 + wave * 16;

    int arow = rowBase + l15;
    if (arow >= NP) arow = NP - 1;
    const float* ap = x + (size_t)arow * 128 + quad * 8;
    bf16x8 ahi[4], alo[4];
#pragma unroll
    for (int kt = 0; kt < 4; ++kt) load_split(ap + kt * 32, ahi[kt], alo[kt]);

    f32x4 acc[4];
#pragma unroll
    for (int ct = 0; ct < 4; ++ct) acc[ct] = (f32x4){0.f, 0.f, 0.f, 0.f};

#pragma unroll
    for (int ct = 0; ct < 4; ++ct) {
#pragma unroll
        for (int kt = 0; kt < 4; ++kt) {
            int f = ct * 4 + kt;
            const bf16x8 bhi = *(const bf16x8*)&Wpk[49152 + f * 512 + lane * 8];
            const bf16x8 blo = *(const bf16x8*)&Wpk[57344 + f * 512 + lane * 8];
            acc[ct] = __builtin_amdgcn_mfma_f32_16x16x32_bf16(ahi[kt], bhi, acc[ct], 0, 0, 0);
            acc[ct] = __builtin_amdgcn_mfma_f32_16x16x32_bf16(ahi[kt], blo, acc[ct], 0, 0, 0);
            acc[ct] = __builtin_amdgcn_mfma_f32_16x16x32_bf16(alo[kt], bhi, acc[ct], 0, 0, 0);
        }
    }

#pragma unroll
    for (int ct = 0; ct < 4; ++ct) {
        int col = ct * 16 + l15;
        float bias = bfp[col];
#pragma unroll
        for (int r = 0; r < 4; ++r) {
            int n = rowBase + quad * 4 + r;
            if (n < NP) xf[(size_t)n * 64 + col] = acc[ct][r] + bias;
        }
    }
}

// per level: x_iou (192 cols, in-register) + Uh_sum/fc_sum -> cell -> h,c (f32 to d_out)
__global__ __launch_bounds__(256) void projcell_kernel(
    const float* __restrict__ x, const unsigned short* __restrict__ Wpk,
    const float* __restrict__ biou,
    const float* __restrict__ uh, const float* __restrict__ fcs,
    float* __restrict__ h_all, float* __restrict__ c_all,
    int s0, int s1, int read_sums)
{
    int wave = threadIdx.x >> 6, lane = threadIdx.x & 63;
    int l15 = lane & 15, quad = lane >> 4;
    int rowBase = blockIdx.x * 64 + wave * 16;    // relative to s0

    int arow = s0 + rowBase + l15;
    if (arow >= s1) arow = s1 - 1;
    const float* ap = x + (size_t)arow * 128 + quad * 8;
    bf16x8 ahi[4], alo[4];
#pragma unroll
    for (int kt = 0; kt < 4; ++kt) load_split(ap + kt * 32, ahi[kt], alo[kt]);

    f32x4 acc[12];
#pragma unroll
    for (int ct = 0; ct < 12; ++ct) acc[ct] = (f32x4){0.f, 0.f, 0.f, 0.f};

#pragma unroll
    for (int ct = 0; ct < 12; ++ct) {
#pragma unroll
        for (int kt = 0; kt < 4; ++kt) {
            int f = ct * 4 + kt;
            const bf16x8 bhi = *(const bf16x8*)&Wpk[f * 512 + lane * 8];
            const bf16x8 blo = *(const bf16x8*)&Wpk[24576 + f * 512 + lane * 8];
            acc[ct] = __builtin_amdgcn_mfma_f32_16x16x32_bf16(ahi[kt], bhi, acc[ct], 0, 0, 0);
            acc[ct] = __builtin_amdgcn_mfma_f32_16x16x32_bf16(ahi[kt], blo, acc[ct], 0, 0, 0);
            acc[ct] = __builtin_amdgcn_mfma_f32_16x16x32_bf16(alo[kt], bhi, acc[ct], 0, 0, 0);
        }
    }

#pragma unroll
    for (int g = 0; g < 4; ++g) {
        int j = g * 16 + l15;
        float bi = biou[j], bo = biou[64 + j], bu = biou[128 + j];
#pragma unroll
        for (int r = 0; r < 4; ++r) {
            int n = s0 + rowBase + quad * 4 + r;
            if (n < s1) {
                float iv = acc[g][r] + bi;
                float ov = acc[4 + g][r] + bo;
                float uv = acc[8 + g][r] + bu;
                float ui = 0.f, uo = 0.f, uu = 0.f, fc0 = 0.f;
                if (read_sums) {
                    size_t b = (size_t)n * 192;
                    ui = uh[b + j]; uo = uh[b + 64 + j]; uu = uh[b + 128 + j];
                    fc0 = fcs[(size_t)n * 64 + j];
                }
                float c = sigmoidf_(iv + ui) * tanhf_(uv + uu) + fc0;
                float h = sigmoidf_(ov + uo) * tanhf_(c);
                h_all[(size_t)n * 64 + j] = h;
                c_all[(size_t)n * 64 + j] = c;
            }
        }
    }
}

// -------- edge GEMM: per (level,mid) bin, chunks of 64 edges/block, MFMA, NO atomics.
// tmp[e-ebase][256] = [Uh (192) | hf (64)] per edge, f32.
__global__ __launch_bounds__(256) void edge_gemm_kernel(
    const float* __restrict__ h_all,
    const unsigned short* __restrict__ Upack,
    const int* __restrict__ bin_off, const int* __restrict__ ord,
    float* __restrict__ tmp, int lvl, int ebase, int nbslots)
{
    __shared__ unsigned short sU[32768];   // [hi 16K][lo 16K] frag-packed, 64 KB

    int bin = lvl * 32 + (blockIdx.x & 31);
    int bslot = blockIdx.x >> 5;
    int off = bin_off[bin];
    int cnt = bin_off[bin + 1] - off;
    if (bslot * 64 >= cnt) return;     // block-uniform, before any barrier

    int mid = bin & 31;
    {
        const float4* src = (const float4*)(Upack + (size_t)mid * 32768);
        float4* dst = (float4*)sU;
        for (int i = threadIdx.x; i < 4096; i += 256) dst[i] = src[i];
    }
    __syncthreads();

    int wid = threadIdx.x >> 6, lane = threadIdx.x & 63;
    int l15 = lane & 15, quad = lane >> 4;

    for (int c = bslot; c * 64 < cnt; c += nbslots) {
        int jrow = c * 64 + wid * 16 + l15;
        int jc = (jrow < cnt) ? jrow : cnt - 1;         // pad: duplicate last edge
        int e = ord[off + jc];
        const float* hp = h_all + (size_t)(e + E0) * 64 + quad * 8;
        bf16x8 ahi[2], alo[2];
        load_split(hp, ahi[0], alo[0]);
        load_split(hp + 32, ahi[1], alo[1]);

        f32x4 acc[16];
#pragma unroll
        for (int ct = 0; ct < 16; ++ct) acc[ct] = (f32x4){0.f, 0.f, 0.f, 0.f};

#pragma unroll
        for (int ct = 0; ct < 16; ++ct) {
#pragma unroll
            for (int kt = 0; kt < 2; ++kt) {
                int f = ct * 2 + kt;
                const bf16x8 bhi = *(const bf16x8*)&sU[f * 512 + lane * 8];
                const bf16x8 blo = *(const bf16x8*)&sU[16384 + f * 512 + lane * 8];
                acc[ct] = __builtin_amdgcn_mfma_f32_16x16x32_bf16(ahi[kt], bhi, acc[ct], 0, 0, 0);
                acc[ct] = __builtin_amdgcn_mfma_f32_16x16x32_bf16(ahi[kt], blo, acc[ct], 0, 0, 0);
                acc[ct] = __builtin_amdgcn_mfma_f32_16x16x32_bf16(alo[kt], bhi, acc[ct], 0, 0, 0);
            }
        }

        // epilogue: C row = quad*4+r (within chunk), col = ct*16+l15
        int rowb = c * 64 + wid * 16 + quad * 4;
#pragma unroll
        for (int r = 0; r < 4; ++r) {
            int jr = rowb + r;
            if (jr < cnt) {
                int e2 = ord[off + jr];
                float* op = tmp + (size_t)(e2 - ebase) * 256 + l15;
#pragma unroll
                for (int ct = 0; ct < 16; ++ct) op[ct * 16] = acc[ct][r];
            }
        }
    }
}

// -------- gather: one wave per parent, sum children tmp rows, write uh/fcs once --------
__global__ __launch_bounds__(256) void scatter_kernel(
    const float* __restrict__ tmp, const float* __restrict__ c_all,
    const float* __restrict__ xf,
    const int* __restrict__ childOff, const int* __restrict__ childList,
    float* __restrict__ uh, float* __restrict__ fcs,
    int p0, int p1, int ebase)
{
    int wid = threadIdx.x >> 6, lane = threadIdx.x & 63;
    int p = p0 + blockIdx.x * 4 + wid;
    if (p >= p1) return;
    int c0 = childOff[p], c1 = childOff[p + 1];
    float u0 = 0.f, u1 = 0.f, u2 = 0.f, fc = 0.f;
    float xfv = xf[(size_t)p * 64 + lane];
    for (int ci = c0; ci < c1; ++ci) {
        int e = childList[ci];
        const float* tp = tmp + (size_t)(e - ebase) * 256;
        u0 += tp[lane];
        u1 += tp[64 + lane];
        u2 += tp[128 + lane];
        float hf = tp[192 + lane];
        fc += sigmoidf_(xfv + hf) * c_all[(size_t)(e + E0) * 64 + lane];
    }
    uh[(size_t)p * 192 + lane] = u0;
    uh[(size_t)p * 192 + 64 + lane] = u1;
    uh[(size_t)p * 192 + 128 + lane] = u2;
    fcs[(size_t)p * 64 + lane] = fc;
}

// -------- fallback (ws too small): original per-edge atomic kernel --------
__global__ __launch_bounds__(256) void edge_kernel(
    const float* __restrict__ h_all, const float* __restrict__ c_all,
    const float* __restrict__ xf,
    float* __restrict__ uh, float* __restrict__ fcs,
    const float* __restrict__ Uiou, const float* __restrict__ Ufm,
    const int* __restrict__ edge_dst, const int* __restrict__ mat_id,
    int s0, int s1)
{
    __shared__ float hbuf[4][64];
    __shared__ float cbuf[4][64];
    int wid = threadIdx.x >> 6, lane = threadIdx.x & 63;
    int n = s0 + blockIdx.x * 4 + wid;
    if (n >= s1) return;

    hbuf[wid][lane] = h_all[(size_t)n * 64 + lane];
    cbuf[wid][lane] = c_all[(size_t)n * 64 + lane];

    int e = n - E0;
    int dst = edge_dst[e];
    int mid = mat_id[e];

    bool isf = (lane >= 48);
    int cb = isf ? 4 * (lane - 48) : 4 * lane;
    const float* p = isf ? (Ufm + (size_t)mid * 4096 + cb)
                         : (Uiou + (size_t)mid * 12288 + cb);
    int stride = isf ? 64 : 192;

    float a0 = 0.f, a1 = 0.f, a2 = 0.f, a3 = 0.f;
    for (int k = 0; k < 64; k += 4) {
        float4 hv = *(const float4*)&hbuf[wid][k];
#pragma unroll
        for (int t = 0; t < 4; ++t) {
            float4 u = *(const float4*)p;
            p += stride;
            float hvt = ((const float*)&hv)[t];
            a0 += hvt * u.x; a1 += hvt * u.y; a2 += hvt * u.z; a3 += hvt * u.w;
        }
    }

    if (isf) {
        size_t d = (size_t)dst * 64 + cb;
        float4 cv = *(const float4*)&cbuf[wid][cb];
        atomicAdd(&fcs[d + 0], sigmoidf_(xf[d + 0] + a0) * cv.x);
        atomicAdd(&fcs[d + 1], sigmoidf_(xf[d + 1] + a1) * cv.y);
        atomicAdd(&fcs[d + 2], sigmoidf_(xf[d + 2] + a2) * cv.z);
        atomicAdd(&fcs[d + 3], sigmoidf_(xf[d + 3] + a3) * cv.w);
    } else {
        size_t d = (size_t)dst * 192 + cb;
        atomicAdd(&uh[d + 0], a0);
        atomicAdd(&uh[d + 1], a1);
        atomicAdd(&uh[d + 2], a2);
        atomicAdd(&uh[d + 3], a3);
    }
}

extern "C" void kernel_launch(void* const* d_in, const int* in_sizes, int n_in,
                              void* d_out, int out_size, void* d_ws, size_t ws_size,
                              hipStream_t stream) {
    const float* x      = (const float*)d_in[0];
    // d_in[1] = edge_src == arange(500, 52500) -> unused
    const int* edge_dst = (const int*)d_in[2];
    const int* mat_id   = (const int*)d_in[3];
    const float* Wiou   = (const float*)d_in[4];
    const float* biou   = (const float*)d_in[5];
    const float* Wf     = (const float*)d_in[6];
    const float* bfp    = (const float*)d_in[7];
    const float* Uiou   = (const float*)d_in[8];
    const float* Ufm    = (const float*)d_in[9];

    // ws layout:
    // [uh NP*192 f32][fcs NP*64][xf NP*64][Wpk 65536 u16][tmp MAXEL*256 f32]
    // [Upack 32*32768 u16]
    // ints: [bin_off 192][ord 52000][childOff 36504][cursor 36500][bincnt 2560]
    //       [bincur 2560][childList 52000][bsum 144]
    float* uh  = (float*)d_ws;
    float* fcs = uh + (size_t)NP * 192;
    float* xf  = fcs + (size_t)NP * 64;
    unsigned short* Wpk = (unsigned short*)(xf + (size_t)NP * 64);
    float* tmp = (float*)(Wpk + 65536);
    unsigned short* Upack = (unsigned short*)(tmp + (size_t)MAXEL * 256);
    int* bin_off   = (int*)(Upack + (size_t)32 * 32768);
    int* ord       = bin_off + 192;
    int* childOff  = ord + NEDGE;
    int* cursor    = childOff + 36504;
    int* bincnt    = cursor + NP;
    int* bincur    = bincnt + 2560;
    int* childList = bincur + 2560;
    int* bsum      = childList + NEDGE;
    size_t need  = (size_t)((char*)(bsum + 144) - (char*)d_ws);
    size_t need2 = (size_t)((char*)tmp - (char*)d_ws);     // fallback: through Wpk
    int grouped = (ws_size >= need) ? 1 : 0;
    if (!grouped && ws_size < need2) return;               // cannot run at all

    float* out_h = (float*)d_out;            // f32 output: h then c
    float* out_c = out_h + (size_t)NN * 64;

    static const int noff[7] = {0, 500, 2500, 8500, 20500, 36500, 52500};

    if (grouped) {
        // setup (once per replay, idempotent under re-poisoned ws)
        // zero cursor(NP) + bincnt(2560) contiguously: 39060 ints = 9765 float4
        zero_kernel<<<(9765 + 255) / 256, 256, 0, stream>>>((float*)cursor, 9765);
        hist_kernel<<<(NEDGE + 255) / 256, 256, 0, stream>>>(edge_dst, mat_id, cursor, bincnt);
        scan1_kernel<<<NSB, 256, 0, stream>>>(cursor, childOff, bsum);
        scan2_kernel<<<1, 256, 0, stream>>>(bsum, bincnt, bin_off, bincur);
        scan3_kernel<<<NSB, 256, 0, stream>>>(childOff, bsum, cursor);
        fill_kernel<<<(NEDGE + 255) / 256, 256, 0, stream>>>(edge_dst, cursor, childList);
        binfill_kernel<<<(NEDGE + 255) / 256, 256, 0, stream>>>(mat_id, bincur, ord);
        upack_kernel<<<32, 256, 0, stream>>>(Uiou, Ufm, Upack);
    } else {
        int n4 = (int)((size_t)NP * 256 / 4);
        zero_kernel<<<(n4 + 255) / 256, 256, 0, stream>>>(uh, n4);
    }
    wpack_kernel<<<128, 256, 0, stream>>>(Wiou, Wf, Wpk);

    xfproj_kernel<<<(NP + 63) / 64, 256, 0, stream>>>(x, Wpk, bfp, xf);

    for (int l = 5; l >= 0; --l) {
        int s0 = noff[l], s1 = noff[l + 1], nl = s1 - s0;
        projcell_kernel<<<(nl + 63) / 64, 256, 0, stream>>>(
            x, Wpk, biou, uh, fcs, out_h, out_c, s0, s1, (l != 5) ? 1 : 0);
        if (l >= 1) {
            if (grouped) {
                int ebase = s0 - E0;
                int nbs = (nl + 2047) / 2048;   // chunk slots per bin
                edge_gemm_kernel<<<32 * nbs, 256, 0, stream>>>(
                    out_h, Upack, bin_off, ord, tmp, l - 1, ebase, nbs);
                int p0 = noff[l - 1], p1 = s0;
                scatter_kernel<<<(p1 - p0 + 3) / 4, 256, 0, stream>>>(
                    tmp, out_c, xf, childOff, childList, uh, fcs, p0, p1, ebase);
            } else {
                edge_kernel<<<(nl + 3) / 4, 256, 0, stream>>>(
                    out_h, out_c, xf, uh, fcs, Uiou, Ufm, edge_dst, mat_id, s0, s1);
            }
        }
    }
}

// Round 5
// 370.215 us; speedup vs baseline: 2.7491x; 1.0628x over previous
//
#include <hip/hip_runtime.h>

#define NN 52500
#define NP 36500            // nodes with children (levels 0..4) = parents
#define E0 500              // edge e corresponds to src node n = e + 500
#define NEDGE 52000
#define NBINS 160           // 5 edge-levels x 32 matrices
#define MAXEL 16000         // max edges in one level
#define NSB 143             // scan blocks = ceil(NP/256)

__device__ __forceinline__ float sigmoidf_(float x) { return 1.f / (1.f + __expf(-x)); }
__device__ __forceinline__ float tanhf_(float x) {
    float e = __expf(-2.f * fabsf(x));
    return copysignf((1.f - e) / (1.f + e), x);
}

typedef __attribute__((ext_vector_type(8))) short bf16x8;
typedef __attribute__((ext_vector_type(4))) float f32x4;

__device__ __forceinline__ unsigned short f2bf_rne(float f) {
    unsigned int u = __float_as_uint(f);
    u += 0x7FFF + ((u >> 16) & 1);
    return (unsigned short)(u >> 16);
}

// load 8 consecutive f32, split each into bf16 hi + bf16 lo (compensated precision ~2^-17)
__device__ __forceinline__ void load_split(const float* p, bf16x8& hi, bf16x8& lo) {
    float4 a = *(const float4*)p;
    float4 b = *(const float4*)(p + 4);
    float v[8] = {a.x, a.y, a.z, a.w, b.x, b.y, b.z, b.w};
#pragma unroll
    for (int j = 0; j < 8; ++j) {
        unsigned short hu = f2bf_rne(v[j]);
        float hf = __uint_as_float((unsigned int)hu << 16);
        hi[j] = (short)hu;
        lo[j] = (short)f2bf_rne(v[j] - hf);
    }
}

__global__ __launch_bounds__(256) void zero_kernel(float* __restrict__ p, int n4) {
    int i = blockIdx.x * 256 + threadIdx.x;
    if (i < n4) ((float4*)p)[i] = (float4){0.f, 0.f, 0.f, 0.f};
}

// -------- CSR hist (by dst) + bin hist (by level,mid), one parallel pass --------
__global__ __launch_bounds__(256) void hist_kernel(const int* __restrict__ edge_dst,
                                                   const int* __restrict__ mat_id,
                                                   int* __restrict__ cnt,
                                                   int* __restrict__ bincnt /*stride 16*/) {
    int e = blockIdx.x * 256 + threadIdx.x;
    if (e < NEDGE) {
        atomicAdd(&cnt[edge_dst[e]], 1);
        int L = (e >= 2000) + (e >= 8000) + (e >= 20000) + (e >= 36000);
        atomicAdd(&bincnt[(L * 32 + mat_id[e]) * 16], 1);
    }
}

// phase 1: per-block scan of counts -> in-block exclusive prefix + per-block sum
__global__ __launch_bounds__(256) void scan1_kernel(const int* __restrict__ cnt,
                                                    int* __restrict__ off,
                                                    int* __restrict__ bsum) {
    __shared__ int s[256];
    int t = threadIdx.x;
    int i = blockIdx.x * 256 + t;
    int v = (i < NP) ? cnt[i] : 0;
    s[t] = v;
    __syncthreads();
#pragma unroll
    for (int d = 1; d < 256; d <<= 1) {
        int u = (t >= d) ? s[t - d] : 0;
        __syncthreads();
        s[t] += u;
        __syncthreads();
    }
    if (i < NP) off[i] = s[t] - v;          // exclusive within block
    if (t == 255) bsum[blockIdx.x] = s[255];
}

// phase 2: exclusive scan of NSB block sums AND exclusive scan of 160 bin counts
__global__ __launch_bounds__(256) void scan2_kernel(int* __restrict__ bsum,
                                                    const int* __restrict__ bincnt,
                                                    int* __restrict__ bin_off,
                                                    int* __restrict__ bincur) {
    __shared__ int s[256];
    __shared__ int b[256];
    int t = threadIdx.x;
    int v = (t < NSB) ? bsum[t] : 0;
    int bv = (t < NBINS) ? bincnt[t * 16] : 0;
    s[t] = v;
    b[t] = bv;
    __syncthreads();
#pragma unroll
    for (int d = 1; d < 256; d <<= 1) {
        int u  = (t >= d) ? s[t - d] : 0;
        int ub = (t >= d) ? b[t - d] : 0;
        __syncthreads();
        s[t] += u;
        b[t] += ub;
        __syncthreads();
    }
    if (t < NSB) bsum[t] = s[t] - v;        // exclusive
    if (t < NBINS) {
        int o = b[t] - bv;                  // exclusive
        bin_off[t] = o;
        bincur[t * 16] = o;
    }
    if (t == 0) bin_off[NBINS] = NEDGE;
}

// phase 3: add block base, finalize childOff, init cursor
__global__ __launch_bounds__(256) void scan3_kernel(int* __restrict__ off,
                                                    const int* __restrict__ bsum,
                                                    int* __restrict__ cursor) {
    int i = blockIdx.x * 256 + threadIdx.x;
    if (i < NP) {
        int o = off[i] + bsum[blockIdx.x];
        off[i] = o;
        cursor[i] = o;
    }
    if (i == 0) off[NP] = NEDGE;            // total children == total edges
}

// CSR fill + bin ord fill in one pass (order within bin/parent irrelevant downstream)
__global__ __launch_bounds__(256) void fill2_kernel(const int* __restrict__ edge_dst,
                                                    const int* __restrict__ mat_id,
                                                    int* __restrict__ cursor,
                                                    int* __restrict__ childList,
                                                    int* __restrict__ bincur,
                                                    int* __restrict__ ord) {
    int e = blockIdx.x * 256 + threadIdx.x;
    if (e < NEDGE) {
        int pos = atomicAdd(&cursor[edge_dst[e]], 1);
        childList[pos] = e;
        int L = (e >= 2000) + (e >= 8000) + (e >= 20000) + (e >= 36000);
        int p2 = atomicAdd(&bincur[(L * 32 + mat_id[e]) * 16], 1);
        ord[p2] = e;
    }
}

// -------- U pack body: [32 mids][hi 16K | lo 16K] bf16 MFMA-B fragments --------
// frag f = ct*2+kt (ct 0..15, kt 0..1); elem(lane,j) = U[kt*32+(lane>>4)*8+j][ct*16+(lane&15)]
// cols 0..191 = U_iou, 192..255 = U_f
__device__ __forceinline__ void upack_body(int mid, int tid,
                                           const float* __restrict__ Uiou,
                                           const float* __restrict__ Ufm,
                                           unsigned short* __restrict__ Upack) {
    unsigned short* dhi = Upack + (size_t)mid * 32768;
    unsigned short* dlo = dhi + 16384;
    for (int p0 = tid * 8; p0 < 16384; p0 += 2048) {
        int f = p0 >> 9;
        int lane = (p0 >> 3) & 63;
        int kt = f & 1, ct = f >> 1;
        int kbase = kt * 32 + (lane >> 4) * 8;
        int col = ct * 16 + (lane & 15);
#pragma unroll
        for (int j = 0; j < 8; ++j) {
            int k = kbase + j;
            float v = (col < 192) ? Uiou[(size_t)mid * 12288 + k * 192 + col]
                                  : Ufm[(size_t)mid * 4096 + k * 64 + (col - 192)];
            unsigned short hu = f2bf_rne(v);
            float hf = __uint_as_float((unsigned int)hu << 16);
            dhi[p0 + j] = hu;
            dlo[p0 + j] = f2bf_rne(v - hf);
        }
    }
}

// -------- W pack body: Wiou (48 frags) + Wf (16 frags), hi/lo, B-fragment layout --------
// frag f=ct*4+kt; elem(lane,j) = W[ct*16+(lane&15)][kt*32+(lane>>4)*8+j]
// layout (ushort): [IOU_HI 0][IOU_LO 24576][F_HI 49152][F_LO 57344], total 65536
__device__ __forceinline__ void wpack_body(int p,
                                           const float* __restrict__ Wiou,
                                           const float* __restrict__ Wf,
                                           unsigned short* __restrict__ Wpk) {
    if (p >= 32768) return;
    int f = p >> 9, lane = (p >> 3) & 63, j = p & 7;
    int l15 = lane & 15, quad = lane >> 4;
    float v;
    int hioff, looff, fi;
    if (f < 48) {
        int ct = f >> 2, kt = f & 3;
        v = Wiou[(size_t)(ct * 16 + l15) * 128 + kt * 32 + quad * 8 + j];
        hioff = 0; looff = 24576; fi = f;
    } else {
        int ff = f - 48;
        int ct = ff >> 2, kt = ff & 3;
        v = Wf[(size_t)(ct * 16 + l15) * 128 + kt * 32 + quad * 8 + j];
        hioff = 49152; looff = 57344; fi = ff;
    }
    unsigned short hu = f2bf_rne(v);
    float hf = __uint_as_float((unsigned int)hu << 16);
    Wpk[hioff + fi * 512 + lane * 8 + j] = hu;
    Wpk[looff + fi * 512 + lane * 8 + j] = f2bf_rne(v - hf);
}

// merged pack: blocks 0..31 -> Upack, blocks 32..159 -> Wpk
__global__ __launch_bounds__(256) void pack_kernel(
    const float* __restrict__ Uiou, const float* __restrict__ Ufm,
    const float* __restrict__ Wiou, const float* __restrict__ Wf,
    unsigned short* __restrict__ Upack, unsigned short* __restrict__ Wpk)
{
    if (blockIdx.x < 32) upack_body(blockIdx.x, threadIdx.x, Uiou, Ufm, Upack);
    else wpack_body((blockIdx.x - 32) * 256 + threadIdx.x, Wiou, Wf, Wpk);
}

__global__ __launch_bounds__(256) void wpack_kernel(
    const float* __restrict__ Wiou, const float* __restrict__ Wf,
    unsigned short* __restrict__ Wpk)
{
    wpack_body(blockIdx.x * 256 + threadIdx.x, Wiou, Wf, Wpk);
}

// -------- FUSED per-level kernel: x_iou + x_f (MFMA, in-register) + CSR gather of
// children edge results from tmp + LSTM cell -> h,c. No uh/fcs/xf intermediates.
__global__ __launch_bounds__(256) void projcell_kernel(
    const float* __restrict__ x, const unsigned short* __restrict__ Wpk,
    const float* __restrict__ biou, const float* __restrict__ bfp,
    const float* __restrict__ tmp,
    const int* __restrict__ childOff, const int* __restrict__ childList,
    float* __restrict__ h_all, float* __restrict__ c_all,
    int s0, int s1, int ebase, int gather)
{
    int wave = threadIdx.x >> 6, lane = threadIdx.x & 63;
    int l15 = lane & 15, quad = lane >> 4;
    int rowBase = blockIdx.x * 64 + wave * 16;    // relative to s0

    int arow = s0 + rowBase + l15;
    if (arow >= s1) arow = s1 - 1;
    const float* ap = x + (size_t)arow * 128 + quad * 8;
    bf16x8 ahi[4], alo[4];
#pragma unroll
    for (int kt = 0; kt < 4; ++kt) load_split(ap + kt * 32, ahi[kt], alo[kt]);

    f32x4 acc[16];
#pragma unroll
    for (int ct = 0; ct < 16; ++ct) acc[ct] = (f32x4){0.f, 0.f, 0.f, 0.f};

    // x_iou: 12 col-tiles (192 cols)
#pragma unroll
    for (int ct = 0; ct < 12; ++ct) {
#pragma unroll
        for (int kt = 0; kt < 4; ++kt) {
            int f = ct * 4 + kt;
            const bf16x8 bhi = *(const bf16x8*)&Wpk[f * 512 + lane * 8];
            const bf16x8 blo = *(const bf16x8*)&Wpk[24576 + f * 512 + lane * 8];
            acc[ct] = __builtin_amdgcn_mfma_f32_16x16x32_bf16(ahi[kt], bhi, acc[ct], 0, 0, 0);
            acc[ct] = __builtin_amdgcn_mfma_f32_16x16x32_bf16(ahi[kt], blo, acc[ct], 0, 0, 0);
            acc[ct] = __builtin_amdgcn_mfma_f32_16x16x32_bf16(alo[kt], bhi, acc[ct], 0, 0, 0);
        }
    }
    // x_f: 4 col-tiles (64 cols), only needed when this level has children
    if (gather) {
#pragma unroll
        for (int g2 = 0; g2 < 4; ++g2) {
#pragma unroll
            for (int kt = 0; kt < 4; ++kt) {
                int f = g2 * 4 + kt;
                const bf16x8 bhi = *(const bf16x8*)&Wpk[49152 + f * 512 + lane * 8];
                const bf16x8 blo = *(const bf16x8*)&Wpk[57344 + f * 512 + lane * 8];
                acc[12 + g2] = __builtin_amdgcn_mfma_f32_16x16x32_bf16(ahi[kt], bhi, acc[12 + g2], 0, 0, 0);
                acc[12 + g2] = __builtin_amdgcn_mfma_f32_16x16x32_bf16(ahi[kt], blo, acc[12 + g2], 0, 0, 0);
                acc[12 + g2] = __builtin_amdgcn_mfma_f32_16x16x32_bf16(alo[kt], bhi, acc[12 + g2], 0, 0, 0);
            }
        }
    }

    // epilogue: lane (l15,quad) holds node n=rowBase+quad*4+r, cols j=16g+l15
#pragma unroll
    for (int r = 0; r < 4; ++r) {
        int n = s0 + rowBase + quad * 4 + r;
        if (n >= s1) continue;
        float ui[4] = {0.f, 0.f, 0.f, 0.f};
        float uo[4] = {0.f, 0.f, 0.f, 0.f};
        float uu[4] = {0.f, 0.f, 0.f, 0.f};
        float fc0[4] = {0.f, 0.f, 0.f, 0.f};
        if (gather) {
            int c0 = childOff[n], c1 = childOff[n + 1];
            float xfv[4];
#pragma unroll
            for (int g = 0; g < 4; ++g) xfv[g] = acc[12 + g][r] + bfp[g * 16 + l15];
            for (int ci = c0; ci < c1; ++ci) {
                int e = childList[ci];
                const float* tp = tmp + (size_t)(e - ebase) * 256;
                const float* cp = c_all + (size_t)(e + E0) * 64;
#pragma unroll
                for (int g = 0; g < 4; ++g) {
                    int j = g * 16 + l15;
                    ui[g] += tp[j];
                    uo[g] += tp[64 + j];
                    uu[g] += tp[128 + j];
                    fc0[g] += sigmoidf_(xfv[g] + tp[192 + j]) * cp[j];
                }
            }
        }
#pragma unroll
        for (int g = 0; g < 4; ++g) {
            int j = g * 16 + l15;
            float iv = acc[g][r] + biou[j];
            float ov = acc[4 + g][r] + biou[64 + j];
            float uv = acc[8 + g][r] + biou[128 + j];
            float cc = sigmoidf_(iv + ui[g]) * tanhf_(uv + uu[g]) + fc0[g];
            float hh = sigmoidf_(ov + uo[g]) * tanhf_(cc);
            h_all[(size_t)n * 64 + j] = hh;
            c_all[(size_t)n * 64 + j] = cc;
        }
    }
}

// -------- edge GEMM: per (level,mid) bin, chunks of 64 edges/block, MFMA, NO atomics.
// tmp[e-ebase][256] = [Uh (192) | hf (64)] per edge, f32.
__global__ __launch_bounds__(256) void edge_gemm_kernel(
    const float* __restrict__ h_all,
    const unsigned short* __restrict__ Upack,
    const int* __restrict__ bin_off, const int* __restrict__ ord,
    float* __restrict__ tmp, int lvl, int ebase, int nbslots)
{
    __shared__ unsigned short sU[32768];   // [hi 16K][lo 16K] frag-packed, 64 KB

    int bin = lvl * 32 + (blockIdx.x & 31);
    int bslot = blockIdx.x >> 5;
    int off = bin_off[bin];
    int cnt = bin_off[bin + 1] - off;
    if (bslot * 64 >= cnt) return;     // block-uniform, before any barrier

    int mid = bin & 31;
    {
        const float4* src = (const float4*)(Upack + (size_t)mid * 32768);
        float4* dst = (float4*)sU;
        for (int i = threadIdx.x; i < 4096; i += 256) dst[i] = src[i];
    }
    __syncthreads();

    int wid = threadIdx.x >> 6, lane = threadIdx.x & 63;
    int l15 = lane & 15, quad = lane >> 4;

    for (int c = bslot; c * 64 < cnt; c += nbslots) {
        int jrow = c * 64 + wid * 16 + l15;
        int jc = (jrow < cnt) ? jrow : cnt - 1;         // pad: duplicate last edge
        int e = ord[off + jc];
        const float* hp = h_all + (size_t)(e + E0) * 64 + quad * 8;
        bf16x8 ahi[2], alo[2];
        load_split(hp, ahi[0], alo[0]);
        load_split(hp + 32, ahi[1], alo[1]);

        f32x4 acc[16];
#pragma unroll
        for (int ct = 0; ct < 16; ++ct) acc[ct] = (f32x4){0.f, 0.f, 0.f, 0.f};

#pragma unroll
        for (int ct = 0; ct < 16; ++ct) {
#pragma unroll
            for (int kt = 0; kt < 2; ++kt) {
                int f = ct * 2 + kt;
                const bf16x8 bhi = *(const bf16x8*)&sU[f * 512 + lane * 8];
                const bf16x8 blo = *(const bf16x8*)&sU[16384 + f * 512 + lane * 8];
                acc[ct] = __builtin_amdgcn_mfma_f32_16x16x32_bf16(ahi[kt], bhi, acc[ct], 0, 0, 0);
                acc[ct] = __builtin_amdgcn_mfma_f32_16x16x32_bf16(ahi[kt], blo, acc[ct], 0, 0, 0);
                acc[ct] = __builtin_amdgcn_mfma_f32_16x16x32_bf16(alo[kt], bhi, acc[ct], 0, 0, 0);
            }
        }

        // epilogue: C row = quad*4+r (within chunk), col = ct*16+l15
        int rowb = c * 64 + wid * 16 + quad * 4;
#pragma unroll
        for (int r = 0; r < 4; ++r) {
            int jr = rowb + r;
            if (jr < cnt) {
                int e2 = ord[off + jr];
                float* op = tmp + (size_t)(e2 - ebase) * 256 + l15;
#pragma unroll
                for (int ct = 0; ct < 16; ++ct) op[ct * 16] = acc[ct][r];
            }
        }
    }
}

// -------- legacy kernels (fallback when ws too small for grouped path) --------
__global__ __launch_bounds__(256) void xfproj_kernel(
    const float* __restrict__ x, const unsigned short* __restrict__ Wpk,
    const float* __restrict__ bfp, float* __restrict__ xf)
{
    int wave = threadIdx.x >> 6, lane = threadIdx.x & 63;
    int l15 = lane & 15, quad = lane >> 4;
    int rowBase = blockIdx.x * 64 + wave * 16;

    int arow = rowBase + l15;
    if (arow >= NP) arow = NP - 1;
    const float* ap = x + (size_t)arow * 128 + quad * 8;
    bf16x8 ahi[4], alo[4];
#pragma unroll
    for (int kt = 0; kt < 4; ++kt) load_split(ap + kt * 32, ahi[kt], alo[kt]);

    f32x4 acc[4];
#pragma unroll
    for (int ct = 0; ct < 4; ++ct) acc[ct] = (f32x4){0.f, 0.f, 0.f, 0.f};

#pragma unroll
    for (int ct = 0; ct < 4; ++ct) {
#pragma unroll
        for (int kt = 0; kt < 4; ++kt) {
            int f = ct * 4 + kt;
            const bf16x8 bhi = *(const bf16x8*)&Wpk[49152 + f * 512 + lane * 8];
            const bf16x8 blo = *(const bf16x8*)&Wpk[57344 + f * 512 + lane * 8];
            acc[ct] = __builtin_amdgcn_mfma_f32_16x16x32_bf16(ahi[kt], bhi, acc[ct], 0, 0, 0);
            acc[ct] = __builtin_amdgcn_mfma_f32_16x16x32_bf16(ahi[kt], blo, acc[ct], 0, 0, 0);
            acc[ct] = __builtin_amdgcn_mfma_f32_16x16x32_bf16(alo[kt], bhi, acc[ct], 0, 0, 0);
        }
    }

#pragma unroll
    for (int ct = 0; ct < 4; ++ct) {
        int col = ct * 16 + l15;
        float bias = bfp[col];
#pragma unroll
        for (int r = 0; r < 4; ++r) {
            int n = rowBase + quad * 4 + r;
            if (n < NP) xf[(size_t)n * 64 + col] = acc[ct][r] + bias;
        }
    }
}

__global__ __launch_bounds__(256) void projcell_legacy_kernel(
    const float* __restrict__ x, const unsigned short* __restrict__ Wpk,
    const float* __restrict__ biou,
    const float* __restrict__ uh, const float* __restrict__ fcs,
    float* __restrict__ h_all, float* __restrict__ c_all,
    int s0, int s1, int read_sums)
{
    int wave = threadIdx.x >> 6, lane = threadIdx.x & 63;
    int l15 = lane & 15, quad = lane >> 4;
    int rowBase = blockIdx.x * 64 + wave * 16;

    int arow = s0 + rowBase + l15;
    if (arow >= s1) arow = s1 - 1;
    const float* ap = x + (size_t)arow * 128 + quad * 8;
    bf16x8 ahi[4], alo[4];
#pragma unroll
    for (int kt = 0; kt < 4; ++kt) load_split(ap + kt * 32, ahi[kt], alo[kt]);

    f32x4 acc[12];
#pragma unroll
    for (int ct = 0; ct < 12; ++ct) acc[ct] = (f32x4){0.f, 0.f, 0.f, 0.f};

#pragma unroll
    for (int ct = 0; ct < 12; ++ct) {
#pragma unroll
        for (int kt = 0; kt < 4; ++kt) {
            int f = ct * 4 + kt;
            const bf16x8 bhi = *(const bf16x8*)&Wpk[f * 512 + lane * 8];
            const bf16x8 blo = *(const bf16x8*)&Wpk[24576 + f * 512 + lane * 8];
            acc[ct] = __builtin_amdgcn_mfma_f32_16x16x32_bf16(ahi[kt], bhi, acc[ct], 0, 0, 0);
            acc[ct] = __builtin_amdgcn_mfma_f32_16x16x32_bf16(ahi[kt], blo, acc[ct], 0, 0, 0);
            acc[ct] = __builtin_amdgcn_mfma_f32_16x16x32_bf16(alo[kt], bhi, acc[ct], 0, 0, 0);
        }
    }

#pragma unroll
    for (int g = 0; g < 4; ++g) {
        int j = g * 16 + l15;
        float bi = biou[j], bo = biou[64 + j], bu = biou[128 + j];
#pragma unroll
        for (int r = 0; r < 4; ++r) {
            int n = s0 + rowBase + quad * 4 + r;
            if (n < s1) {
                float iv = acc[g][r] + bi;
                float ov = acc[4 + g][r] + bo;
                float uv = acc[8 + g][r] + bu;
                float ui = 0.f, uo = 0.f, uu = 0.f, fc0 = 0.f;
                if (read_sums) {
                    size_t b = (size_t)n * 192;
                    ui = uh[b + j]; uo = uh[b + 64 + j]; uu = uh[b + 128 + j];
                    fc0 = fcs[(size_t)n * 64 + j];
                }
                float c = sigmoidf_(iv + ui) * tanhf_(uv + uu) + fc0;
                float h = sigmoidf_(ov + uo) * tanhf_(c);
                h_all[(size_t)n * 64 + j] = h;
                c_all[(size_t)n * 64 + j] = c;
            }
        }
    }
}

__global__ __launch_bounds__(256) void edge_kernel(
    const float* __restrict__ h_all, const float* __restrict__ c_all,
    const float* __restrict__ xf,
    float* __restrict__ uh, float* __restrict__ fcs,
    const float* __restrict__ Uiou, const float* __restrict__ Ufm,
    const int* __restrict__ edge_dst, const int* __restrict__ mat_id,
    int s0, int s1)
{
    __shared__ float hbuf[4][64];
    __shared__ float cbuf[4][64];
    int wid = threadIdx.x >> 6, lane = threadIdx.x & 63;
    int n = s0 + blockIdx.x * 4 + wid;
    if (n >= s1) return;

    hbuf[wid][lane] = h_all[(size_t)n * 64 + lane];
    cbuf[wid][lane] = c_all[(size_t)n * 64 + lane];

    int e = n - E0;
    int dst = edge_dst[e];
    int mid = mat_id[e];

    bool isf = (lane >= 48);
    int cb = isf ? 4 * (lane - 48) : 4 * lane;
    const float* p = isf ? (Ufm + (size_t)mid * 4096 + cb)
                         : (Uiou + (size_t)mid * 12288 + cb);
    int stride = isf ? 64 : 192;

    float a0 = 0.f, a1 = 0.f, a2 = 0.f, a3 = 0.f;
    for (int k = 0; k < 64; k += 4) {
        float4 hv = *(const float4*)&hbuf[wid][k];
#pragma unroll
        for (int t = 0; t < 4; ++t) {
            float4 u = *(const float4*)p;
            p += stride;
            float hvt = ((const float*)&hv)[t];
            a0 += hvt * u.x; a1 += hvt * u.y; a2 += hvt * u.z; a3 += hvt * u.w;
        }
    }

    if (isf) {
        size_t d = (size_t)dst * 64 + cb;
        float4 cv = *(const float4*)&cbuf[wid][cb];
        atomicAdd(&fcs[d + 0], sigmoidf_(xf[d + 0] + a0) * cv.x);
        atomicAdd(&fcs[d + 1], sigmoidf_(xf[d + 1] + a1) * cv.y);
        atomicAdd(&fcs[d + 2], sigmoidf_(xf[d + 2] + a2) * cv.z);
        atomicAdd(&fcs[d + 3], sigmoidf_(xf[d + 3] + a3) * cv.w);
    } else {
        size_t d = (size_t)dst * 192 + cb;
        atomicAdd(&uh[d + 0], a0);
        atomicAdd(&uh[d + 1], a1);
        atomicAdd(&uh[d + 2], a2);
        atomicAdd(&uh[d + 3], a3);
    }
}

extern "C" void kernel_launch(void* const* d_in, const int* in_sizes, int n_in,
                              void* d_out, int out_size, void* d_ws, size_t ws_size,
                              hipStream_t stream) {
    const float* x      = (const float*)d_in[0];
    // d_in[1] = edge_src == arange(500, 52500) -> unused
    const int* edge_dst = (const int*)d_in[2];
    const int* mat_id   = (const int*)d_in[3];
    const float* Wiou   = (const float*)d_in[4];
    const float* biou   = (const float*)d_in[5];
    const float* Wf     = (const float*)d_in[6];
    const float* bfp    = (const float*)d_in[7];
    const float* Uiou   = (const float*)d_in[8];
    const float* Ufm    = (const float*)d_in[9];

    // ws layout (kept identical to R3 for stability; uh/fcs/xf used only by fallback):
    // [uh NP*192 f32][fcs NP*64][xf NP*64][Wpk 65536 u16][tmp MAXEL*256 f32]
    // [Upack 32*32768 u16]
    // ints: [bin_off 192][ord 52000][childOff 36504][cursor 36500][bincnt 2560]
    //       [bincur 2560][childList 52000][bsum 144]
    float* uh  = (float*)d_ws;
    float* fcs = uh + (size_t)NP * 192;
    float* xf  = fcs + (size_t)NP * 64;
    unsigned short* Wpk = (unsigned short*)(xf + (size_t)NP * 64);
    float* tmp = (float*)(Wpk + 65536);
    unsigned short* Upack = (unsigned short*)(tmp + (size_t)MAXEL * 256);
    int* bin_off   = (int*)(Upack + (size_t)32 * 32768);
    int* ord       = bin_off + 192;
    int* childOff  = ord + NEDGE;
    int* cursor    = childOff + 36504;
    int* bincnt    = cursor + NP;
    int* bincur    = bincnt + 2560;
    int* childList = bincur + 2560;
    int* bsum      = childList + NEDGE;
    size_t need  = (size_t)((char*)(bsum + 144) - (char*)d_ws);
    size_t need2 = (size_t)((char*)tmp - (char*)d_ws);     // fallback: through Wpk
    int grouped = (ws_size >= need) ? 1 : 0;
    if (!grouped && ws_size < need2) return;               // cannot run at all

    float* out_h = (float*)d_out;            // f32 output: h then c
    float* out_c = out_h + (size_t)NN * 64;

    static const int noff[7] = {0, 500, 2500, 8500, 20500, 36500, 52500};

    if (grouped) {
        // setup (per replay; ws is re-poisoned): zero cursor(36500)+bincnt(2560) = 39060 ints
        zero_kernel<<<(9765 + 255) / 256, 256, 0, stream>>>((float*)cursor, 9765);
        hist_kernel<<<(NEDGE + 255) / 256, 256, 0, stream>>>(edge_dst, mat_id, cursor, bincnt);
        scan1_kernel<<<NSB, 256, 0, stream>>>(cursor, childOff, bsum);
        scan2_kernel<<<1, 256, 0, stream>>>(bsum, bincnt, bin_off, bincur);
        scan3_kernel<<<NSB, 256, 0, stream>>>(childOff, bsum, cursor);
        fill2_kernel<<<(NEDGE + 255) / 256, 256, 0, stream>>>(
            edge_dst, mat_id, cursor, childList, bincur, ord);
        pack_kernel<<<160, 256, 0, stream>>>(Uiou, Ufm, Wiou, Wf, Upack, Wpk);

        for (int l = 5; l >= 0; --l) {
            int s0 = noff[l], s1 = noff[l + 1], nl = s1 - s0;
            int gather = (l != 5) ? 1 : 0;
            int gebase = gather ? (noff[l + 1] - E0) : 0;   // edges at level l+1
            projcell_kernel<<<(nl + 63) / 64, 256, 0, stream>>>(
                x, Wpk, biou, bfp, tmp, childOff, childList,
                out_h, out_c, s0, s1, gebase, gather);
            if (l >= 1) {
                int ebase = s0 - E0;
                int nbs = (nl + 2047) / 2048;   // chunk slots per bin
                edge_gemm_kernel<<<32 * nbs, 256, 0, stream>>>(
                    out_h, Upack, bin_off, ord, tmp, l - 1, ebase, nbs);
            }
        }
    } else {
        int n4 = (int)((size_t)NP * 256 / 4);
        zero_kernel<<<(n4 + 255) / 256, 256, 0, stream>>>(uh, n4);
        wpack_kernel<<<128, 256, 0, stream>>>(Wiou, Wf, Wpk);
        xfproj_kernel<<<(NP + 63) / 64, 256, 0, stream>>>(x, Wpk, bfp, xf);
        for (int l = 5; l >= 0; --l) {
            int s0 = noff[l], s1 = noff[l + 1], nl = s1 - s0;
            projcell_legacy_kernel<<<(nl + 63) / 64, 256, 0, stream>>>(
                x, Wpk, biou, uh, fcs, out_h, out_c, s0, s1, (l != 5) ? 1 : 0);
            if (l >= 1) {
                edge_kernel<<<(nl + 3) / 4, 256, 0, stream>>>(
                    out_h, out_c, xf, uh, fcs, Uiou, Ufm, edge_dst, mat_id, s0, s1);
            }
        }
    }
}

// Round 6
// 356.301 us; speedup vs baseline: 2.8565x; 1.0391x over previous
//
#include <hip/hip_runtime.h>

#define NN 52500
#define NP 36500            // nodes with children (levels 0..4) = parents
#define E0 500              // edge e corresponds to src node n = e + 500
#define NEDGE 52000
#define NBINS 160           // 5 edge-levels x 32 matrices
#define MAXEL 16000         // max edges in one level
#define NSB 143             // scan blocks = ceil(NP/256)

__device__ __forceinline__ float sigmoidf_(float x) { return 1.f / (1.f + __expf(-x)); }
__device__ __forceinline__ float tanhf_(float x) {
    float e = __expf(-2.f * fabsf(x));
    return copysignf((1.f - e) / (1.f + e), x);
}

typedef __attribute__((ext_vector_type(8))) short bf16x8;
typedef __attribute__((ext_vector_type(4))) float f32x4;

__device__ __forceinline__ unsigned short f2bf_rne(float f) {
    unsigned int u = __float_as_uint(f);
    u += 0x7FFF + ((u >> 16) & 1);
    return (unsigned short)(u >> 16);
}

// load 8 consecutive f32, split each into bf16 hi + bf16 lo (compensated precision ~2^-17)
__device__ __forceinline__ void load_split(const float* p, bf16x8& hi, bf16x8& lo) {
    float4 a = *(const float4*)p;
    float4 b = *(const float4*)(p + 4);
    float v[8] = {a.x, a.y, a.z, a.w, b.x, b.y, b.z, b.w};
#pragma unroll
    for (int j = 0; j < 8; ++j) {
        unsigned short hu = f2bf_rne(v[j]);
        float hf = __uint_as_float((unsigned int)hu << 16);
        hi[j] = (short)hu;
        lo[j] = (short)f2bf_rne(v[j] - hf);
    }
}

__global__ __launch_bounds__(256) void zero_kernel(float* __restrict__ p, int n4) {
    int i = blockIdx.x * 256 + threadIdx.x;
    if (i < n4) ((float4*)p)[i] = (float4){0.f, 0.f, 0.f, 0.f};
}

// -------- U pack body: [32 mids][hi 16K | lo 16K] bf16 MFMA-B fragments --------
// frag f = ct*2+kt (ct 0..15, kt 0..1); elem(lane,j) = U[kt*32+(lane>>4)*8+j][ct*16+(lane&15)]
// cols 0..191 = U_iou, 192..255 = U_f
__device__ __forceinline__ void upack_body(int mid, int tid,
                                           const float* __restrict__ Uiou,
                                           const float* __restrict__ Ufm,
                                           unsigned short* __restrict__ Upack) {
    unsigned short* dhi = Upack + (size_t)mid * 32768;
    unsigned short* dlo = dhi + 16384;
    for (int p0 = tid * 8; p0 < 16384; p0 += 2048) {
        int f = p0 >> 9;
        int lane = (p0 >> 3) & 63;
        int kt = f & 1, ct = f >> 1;
        int kbase = kt * 32 + (lane >> 4) * 8;
        int col = ct * 16 + (lane & 15);
#pragma unroll
        for (int j = 0; j < 8; ++j) {
            int k = kbase + j;
            float v = (col < 192) ? Uiou[(size_t)mid * 12288 + k * 192 + col]
                                  : Ufm[(size_t)mid * 4096 + k * 64 + (col - 192)];
            unsigned short hu = f2bf_rne(v);
            float hf = __uint_as_float((unsigned int)hu << 16);
            dhi[p0 + j] = hu;
            dlo[p0 + j] = f2bf_rne(v - hf);
        }
    }
}

// -------- W pack body: Wiou (48 frags) + Wf (16 frags), hi/lo, B-fragment layout --------
// frag f=ct*4+kt; elem(lane,j) = W[ct*16+(lane&15)][kt*32+(lane>>4)*8+j]
// layout (ushort): [IOU_HI 0][IOU_LO 24576][F_HI 49152][F_LO 57344], total 65536
__device__ __forceinline__ void wpack_body(int p,
                                           const float* __restrict__ Wiou,
                                           const float* __restrict__ Wf,
                                           unsigned short* __restrict__ Wpk) {
    if (p >= 32768) return;
    int f = p >> 9, lane = (p >> 3) & 63, j = p & 7;
    int l15 = lane & 15, quad = lane >> 4;
    float v;
    int hioff, looff, fi;
    if (f < 48) {
        int ct = f >> 2, kt = f & 3;
        v = Wiou[(size_t)(ct * 16 + l15) * 128 + kt * 32 + quad * 8 + j];
        hioff = 0; looff = 24576; fi = f;
    } else {
        int ff = f - 48;
        int ct = ff >> 2, kt = ff & 3;
        v = Wf[(size_t)(ct * 16 + l15) * 128 + kt * 32 + quad * 8 + j];
        hioff = 49152; looff = 57344; fi = ff;
    }
    unsigned short hu = f2bf_rne(v);
    float hf = __uint_as_float((unsigned int)hu << 16);
    Wpk[hioff + fi * 512 + lane * 8 + j] = hu;
    Wpk[looff + fi * 512 + lane * 8 + j] = f2bf_rne(v - hf);
}

// -------- merged: CSR hist + bin hist (blocks 0..203) AND U/W pack (blocks 204..363) ----
__global__ __launch_bounds__(256) void histpack_kernel(
    const int* __restrict__ edge_dst, const int* __restrict__ mat_id,
    int* __restrict__ cnt, int* __restrict__ bincnt /*stride 16*/,
    const float* __restrict__ Uiou, const float* __restrict__ Ufm,
    const float* __restrict__ Wiou, const float* __restrict__ Wf,
    unsigned short* __restrict__ Upack, unsigned short* __restrict__ Wpk)
{
    int b = blockIdx.x;
    if (b < 204) {
        int e = b * 256 + threadIdx.x;
        if (e < NEDGE) {
            atomicAdd(&cnt[edge_dst[e]], 1);
            int L = (e >= 2000) + (e >= 8000) + (e >= 20000) + (e >= 36000);
            atomicAdd(&bincnt[(L * 32 + mat_id[e]) * 16], 1);
        }
    } else if (b < 236) {
        upack_body(b - 204, threadIdx.x, Uiou, Ufm, Upack);
    } else {
        wpack_body((b - 236) * 256 + threadIdx.x, Wiou, Wf, Wpk);
    }
}

// phase 1: per-block scan of counts -> in-block exclusive prefix + per-block sum
__global__ __launch_bounds__(256) void scan1_kernel(const int* __restrict__ cnt,
                                                    int* __restrict__ off,
                                                    int* __restrict__ bsum) {
    __shared__ int s[256];
    int t = threadIdx.x;
    int i = blockIdx.x * 256 + t;
    int v = (i < NP) ? cnt[i] : 0;
    s[t] = v;
    __syncthreads();
#pragma unroll
    for (int d = 1; d < 256; d <<= 1) {
        int u = (t >= d) ? s[t - d] : 0;
        __syncthreads();
        s[t] += u;
        __syncthreads();
    }
    if (i < NP) off[i] = s[t] - v;          // exclusive within block
    if (t == 255) bsum[blockIdx.x] = s[255];
}

// phase 2: exclusive scan of NSB block sums AND exclusive scan of 160 bin counts
__global__ __launch_bounds__(256) void scan2_kernel(int* __restrict__ bsum,
                                                    const int* __restrict__ bincnt,
                                                    int* __restrict__ bin_off,
                                                    int* __restrict__ bincur) {
    __shared__ int s[256];
    __shared__ int b[256];
    int t = threadIdx.x;
    int v = (t < NSB) ? bsum[t] : 0;
    int bv = (t < NBINS) ? bincnt[t * 16] : 0;
    s[t] = v;
    b[t] = bv;
    __syncthreads();
#pragma unroll
    for (int d = 1; d < 256; d <<= 1) {
        int u  = (t >= d) ? s[t - d] : 0;
        int ub = (t >= d) ? b[t - d] : 0;
        __syncthreads();
        s[t] += u;
        b[t] += ub;
        __syncthreads();
    }
    if (t < NSB) bsum[t] = s[t] - v;        // exclusive
    if (t < NBINS) {
        int o = b[t] - bv;                  // exclusive
        bin_off[t] = o;
        bincur[t * 16] = o;
    }
    if (t == 0) bin_off[NBINS] = NEDGE;
}

// phase 3: add block base, finalize childOff, init cursor
__global__ __launch_bounds__(256) void scan3_kernel(int* __restrict__ off,
                                                    const int* __restrict__ bsum,
                                                    int* __restrict__ cursor) {
    int i = blockIdx.x * 256 + threadIdx.x;
    if (i < NP) {
        int o = off[i] + bsum[blockIdx.x];
        off[i] = o;
        cursor[i] = o;
    }
    if (i == 0) off[NP] = NEDGE;            // total children == total edges
}

// CSR fill + bin ord fill in one pass (order within bin/parent irrelevant downstream)
__global__ __launch_bounds__(256) void fill2_kernel(const int* __restrict__ edge_dst,
                                                    const int* __restrict__ mat_id,
                                                    int* __restrict__ cursor,
                                                    int* __restrict__ childList,
                                                    int* __restrict__ bincur,
                                                    int* __restrict__ ord) {
    int e = blockIdx.x * 256 + threadIdx.x;
    if (e < NEDGE) {
        int pos = atomicAdd(&cursor[edge_dst[e]], 1);
        childList[pos] = e;
        int L = (e >= 2000) + (e >= 8000) + (e >= 20000) + (e >= 36000);
        int p2 = atomicAdd(&bincur[(L * 32 + mat_id[e]) * 16], 1);
        ord[p2] = e;
    }
}

__global__ __launch_bounds__(256) void wpack_kernel(
    const float* __restrict__ Wiou, const float* __restrict__ Wf,
    unsigned short* __restrict__ Wpk)
{
    wpack_body(blockIdx.x * 256 + threadIdx.x, Wiou, Wf, Wpk);
}

// -------- FUSED per-level kernel: x_iou + x_f (MFMA, in-register) + CSR gather of
// children edge results from tmp + LSTM cell -> h,c. No uh/fcs/xf intermediates.
__global__ __launch_bounds__(256) void projcell_kernel(
    const float* __restrict__ x, const unsigned short* __restrict__ Wpk,
    const float* __restrict__ biou, const float* __restrict__ bfp,
    const float* __restrict__ tmp,
    const int* __restrict__ childOff, const int* __restrict__ childList,
    float* __restrict__ h_all, float* __restrict__ c_all,
    int s0, int s1, int ebase, int gather)
{
    int wave = threadIdx.x >> 6, lane = threadIdx.x & 63;
    int l15 = lane & 15, quad = lane >> 4;
    int rowBase = blockIdx.x * 64 + wave * 16;    // relative to s0

    int arow = s0 + rowBase + l15;
    if (arow >= s1) arow = s1 - 1;
    const float* ap = x + (size_t)arow * 128 + quad * 8;
    bf16x8 ahi[4], alo[4];
#pragma unroll
    for (int kt = 0; kt < 4; ++kt) load_split(ap + kt * 32, ahi[kt], alo[kt]);

    f32x4 acc[16];
#pragma unroll
    for (int ct = 0; ct < 16; ++ct) acc[ct] = (f32x4){0.f, 0.f, 0.f, 0.f};

    // x_iou: 12 col-tiles (192 cols)
#pragma unroll
    for (int ct = 0; ct < 12; ++ct) {
#pragma unroll
        for (int kt = 0; kt < 4; ++kt) {
            int f = ct * 4 + kt;
            const bf16x8 bhi = *(const bf16x8*)&Wpk[f * 512 + lane * 8];
            const bf16x8 blo = *(const bf16x8*)&Wpk[24576 + f * 512 + lane * 8];
            acc[ct] = __builtin_amdgcn_mfma_f32_16x16x32_bf16(ahi[kt], bhi, acc[ct], 0, 0, 0);
            acc[ct] = __builtin_amdgcn_mfma_f32_16x16x32_bf16(ahi[kt], blo, acc[ct], 0, 0, 0);
            acc[ct] = __builtin_amdgcn_mfma_f32_16x16x32_bf16(alo[kt], bhi, acc[ct], 0, 0, 0);
        }
    }
    // x_f: 4 col-tiles (64 cols), only needed when this level has children
    if (gather) {
#pragma unroll
        for (int g2 = 0; g2 < 4; ++g2) {
#pragma unroll
            for (int kt = 0; kt < 4; ++kt) {
                int f = g2 * 4 + kt;
                const bf16x8 bhi = *(const bf16x8*)&Wpk[49152 + f * 512 + lane * 8];
                const bf16x8 blo = *(const bf16x8*)&Wpk[57344 + f * 512 + lane * 8];
                acc[12 + g2] = __builtin_amdgcn_mfma_f32_16x16x32_bf16(ahi[kt], bhi, acc[12 + g2], 0, 0, 0);
                acc[12 + g2] = __builtin_amdgcn_mfma_f32_16x16x32_bf16(ahi[kt], blo, acc[12 + g2], 0, 0, 0);
                acc[12 + g2] = __builtin_amdgcn_mfma_f32_16x16x32_bf16(alo[kt], bhi, acc[12 + g2], 0, 0, 0);
            }
        }
    }

    // epilogue: lane (l15,quad) holds node n=rowBase+quad*4+r, cols j=16g+l15
#pragma unroll
    for (int r = 0; r < 4; ++r) {
        int n = s0 + rowBase + quad * 4 + r;
        if (n >= s1) continue;
        float ui[4] = {0.f, 0.f, 0.f, 0.f};
        float uo[4] = {0.f, 0.f, 0.f, 0.f};
        float uu[4] = {0.f, 0.f, 0.f, 0.f};
        float fc0[4] = {0.f, 0.f, 0.f, 0.f};
        if (gather) {
            int c0 = childOff[n], c1 = childOff[n + 1];
            float xfv[4];
#pragma unroll
            for (int g = 0; g < 4; ++g) xfv[g] = acc[12 + g][r] + bfp[g * 16 + l15];
            for (int ci = c0; ci < c1; ++ci) {
                int e = childList[ci];
                const float* tp = tmp + (size_t)(e - ebase) * 256;
                const float* cp = c_all + (size_t)(e + E0) * 64;
#pragma unroll
                for (int g = 0; g < 4; ++g) {
                    int j = g * 16 + l15;
                    ui[g] += tp[j];
                    uo[g] += tp[64 + j];
                    uu[g] += tp[128 + j];
                    fc0[g] += sigmoidf_(xfv[g] + tp[192 + j]) * cp[j];
                }
            }
        }
#pragma unroll
        for (int g = 0; g < 4; ++g) {
            int j = g * 16 + l15;
            float iv = acc[g][r] + biou[j];
            float ov = acc[4 + g][r] + biou[64 + j];
            float uv = acc[8 + g][r] + biou[128 + j];
            float cc = sigmoidf_(iv + ui[g]) * tanhf_(uv + uu[g]) + fc0[g];
            float hh = sigmoidf_(ov + uo[g]) * tanhf_(cc);
            h_all[(size_t)n * 64 + j] = hh;
            c_all[(size_t)n * 64 + j] = cc;
        }
    }
}

// -------- edge GEMM: LDS-free. Per (level,mid) bin, each WAVE handles 16-edge chunks,
// B-fragments streamed directly from L2-resident Upack. NO staging, NO barriers.
// tmp[e-ebase][256] = [Uh (192) | hf (64)] per edge, f32.
__global__ __launch_bounds__(256) void edge_gemm_kernel(
    const float* __restrict__ h_all,
    const unsigned short* __restrict__ Upack,
    const int* __restrict__ bin_off, const int* __restrict__ ord,
    float* __restrict__ tmp, int lvl, int ebase, int nbslots)
{
    int bin = lvl * 32 + (blockIdx.x & 31);
    int bslot = blockIdx.x >> 5;
    int off = bin_off[bin];
    int cnt = bin_off[bin + 1] - off;
    int mid = bin & 31;
    const unsigned short* Uhi = Upack + (size_t)mid * 32768;
    const unsigned short* Ulo = Uhi + 16384;

    int wid = threadIdx.x >> 6, lane = threadIdx.x & 63;
    int l15 = lane & 15, quad = lane >> 4;

    // wave-granular chunks of 16 edges
    for (int j0 = (bslot * 4 + wid) * 16; j0 < cnt; j0 += nbslots * 64) {
        int jc = j0 + l15; if (jc > cnt - 1) jc = cnt - 1;   // pad: duplicate last edge
        int e = ord[off + jc];
        const float* hp = h_all + (size_t)(e + E0) * 64 + quad * 8;
        bf16x8 ahi[2], alo[2];
        load_split(hp, ahi[0], alo[0]);
        load_split(hp + 32, ahi[1], alo[1]);

        f32x4 acc[16];
#pragma unroll
        for (int ct = 0; ct < 16; ++ct) acc[ct] = (f32x4){0.f, 0.f, 0.f, 0.f};

#pragma unroll
        for (int ct = 0; ct < 16; ++ct) {
#pragma unroll
            for (int kt = 0; kt < 2; ++kt) {
                int f = ct * 2 + kt;
                const bf16x8 bhi = *(const bf16x8*)&Uhi[f * 512 + lane * 8];
                const bf16x8 blo = *(const bf16x8*)&Ulo[f * 512 + lane * 8];
                acc[ct] = __builtin_amdgcn_mfma_f32_16x16x32_bf16(ahi[kt], bhi, acc[ct], 0, 0, 0);
                acc[ct] = __builtin_amdgcn_mfma_f32_16x16x32_bf16(ahi[kt], blo, acc[ct], 0, 0, 0);
                acc[ct] = __builtin_amdgcn_mfma_f32_16x16x32_bf16(alo[kt], bhi, acc[ct], 0, 0, 0);
            }
        }

        // epilogue: C row = quad*4+r (within the 16-edge chunk), col = ct*16+l15
#pragma unroll
        for (int r = 0; r < 4; ++r) {
            int jr = j0 + quad * 4 + r;
            if (jr < cnt) {
                int e2 = ord[off + jr];
                float* op = tmp + (size_t)(e2 - ebase) * 256 + l15;
#pragma unroll
                for (int ct = 0; ct < 16; ++ct) op[ct * 16] = acc[ct][r];
            }
        }
    }
}

// -------- legacy kernels (fallback when ws too small for grouped path) --------
__global__ __launch_bounds__(256) void xfproj_kernel(
    const float* __restrict__ x, const unsigned short* __restrict__ Wpk,
    const float* __restrict__ bfp, float* __restrict__ xf)
{
    int wave = threadIdx.x >> 6, lane = threadIdx.x & 63;
    int l15 = lane & 15, quad = lane >> 4;
    int rowBase = blockIdx.x * 64 + wave * 16;

    int arow = rowBase + l15;
    if (arow >= NP) arow = NP - 1;
    const float* ap = x + (size_t)arow * 128 + quad * 8;
    bf16x8 ahi[4], alo[4];
#pragma unroll
    for (int kt = 0; kt < 4; ++kt) load_split(ap + kt * 32, ahi[kt], alo[kt]);

    f32x4 acc[4];
#pragma unroll
    for (int ct = 0; ct < 4; ++ct) acc[ct] = (f32x4){0.f, 0.f, 0.f, 0.f};

#pragma unroll
    for (int ct = 0; ct < 4; ++ct) {
#pragma unroll
        for (int kt = 0; kt < 4; ++kt) {
            int f = ct * 4 + kt;
            const bf16x8 bhi = *(const bf16x8*)&Wpk[49152 + f * 512 + lane * 8];
            const bf16x8 blo = *(const bf16x8*)&Wpk[57344 + f * 512 + lane * 8];
            acc[ct] = __builtin_amdgcn_mfma_f32_16x16x32_bf16(ahi[kt], bhi, acc[ct], 0, 0, 0);
            acc[ct] = __builtin_amdgcn_mfma_f32_16x16x32_bf16(ahi[kt], blo, acc[ct], 0, 0, 0);
            acc[ct] = __builtin_amdgcn_mfma_f32_16x16x32_bf16(alo[kt], bhi, acc[ct], 0, 0, 0);
        }
    }

#pragma unroll
    for (int ct = 0; ct < 4; ++ct) {
        int col = ct * 16 + l15;
        float bias = bfp[col];
#pragma unroll
        for (int r = 0; r < 4; ++r) {
            int n = rowBase + quad * 4 + r;
            if (n < NP) xf[(size_t)n * 64 + col] = acc[ct][r] + bias;
        }
    }
}

__global__ __launch_bounds__(256) void projcell_legacy_kernel(
    const float* __restrict__ x, const unsigned short* __restrict__ Wpk,
    const float* __restrict__ biou,
    const float* __restrict__ uh, const float* __restrict__ fcs,
    float* __restrict__ h_all, float* __restrict__ c_all,
    int s0, int s1, int read_sums)
{
    int wave = threadIdx.x >> 6, lane = threadIdx.x & 63;
    int l15 = lane & 15, quad = lane >> 4;
    int rowBase = blockIdx.x * 64 + wave * 16;

    int arow = s0 + rowBase + l15;
    if (arow >= s1) arow = s1 - 1;
    const float* ap = x + (size_t)arow * 128 + quad * 8;
    bf16x8 ahi[4], alo[4];
#pragma unroll
    for (int kt = 0; kt < 4; ++kt) load_split(ap + kt * 32, ahi[kt], alo[kt]);

    f32x4 acc[12];
#pragma unroll
    for (int ct = 0; ct < 12; ++ct) acc[ct] = (f32x4){0.f, 0.f, 0.f, 0.f};

#pragma unroll
    for (int ct = 0; ct < 12; ++ct) {
#pragma unroll
        for (int kt = 0; kt < 4; ++kt) {
            int f = ct * 4 + kt;
            const bf16x8 bhi = *(const bf16x8*)&Wpk[f * 512 + lane * 8];
            const bf16x8 blo = *(const bf16x8*)&Wpk[24576 + f * 512 + lane * 8];
            acc[ct] = __builtin_amdgcn_mfma_f32_16x16x32_bf16(ahi[kt], bhi, acc[ct], 0, 0, 0);
            acc[ct] = __builtin_amdgcn_mfma_f32_16x16x32_bf16(ahi[kt], blo, acc[ct], 0, 0, 0);
            acc[ct] = __builtin_amdgcn_mfma_f32_16x16x32_bf16(alo[kt], bhi, acc[ct], 0, 0, 0);
        }
    }

#pragma unroll
    for (int g = 0; g < 4; ++g) {
        int j = g * 16 + l15;
        float bi = biou[j], bo = biou[64 + j], bu = biou[128 + j];
#pragma unroll
        for (int r = 0; r < 4; ++r) {
            int n = s0 + rowBase + quad * 4 + r;
            if (n < s1) {
                float iv = acc[g][r] + bi;
                float ov = acc[4 + g][r] + bo;
                float uv = acc[8 + g][r] + bu;
                float ui = 0.f, uo = 0.f, uu = 0.f, fc0 = 0.f;
                if (read_sums) {
                    size_t b = (size_t)n * 192;
                    ui = uh[b + j]; uo = uh[b + 64 + j]; uu = uh[b + 128 + j];
                    fc0 = fcs[(size_t)n * 64 + j];
                }
                float c = sigmoidf_(iv + ui) * tanhf_(uv + uu) + fc0;
                float h = sigmoidf_(ov + uo) * tanhf_(c);
                h_all[(size_t)n * 64 + j] = h;
                c_all[(size_t)n * 64 + j] = c;
            }
        }
    }
}

__global__ __launch_bounds__(256) void edge_kernel(
    const float* __restrict__ h_all, const float* __restrict__ c_all,
    const float* __restrict__ xf,
    float* __restrict__ uh, float* __restrict__ fcs,
    const float* __restrict__ Uiou, const float* __restrict__ Ufm,
    const int* __restrict__ edge_dst, const int* __restrict__ mat_id,
    int s0, int s1)
{
    __shared__ float hbuf[4][64];
    __shared__ float cbuf[4][64];
    int wid = threadIdx.x >> 6, lane = threadIdx.x & 63;
    int n = s0 + blockIdx.x * 4 + wid;
    if (n >= s1) return;

    hbuf[wid][lane] = h_all[(size_t)n * 64 + lane];
    cbuf[wid][lane] = c_all[(size_t)n * 64 + lane];

    int e = n - E0;
    int dst = edge_dst[e];
    int mid = mat_id[e];

    bool isf = (lane >= 48);
    int cb = isf ? 4 * (lane - 48) : 4 * lane;
    const float* p = isf ? (Ufm + (size_t)mid * 4096 + cb)
                         : (Uiou + (size_t)mid * 12288 + cb);
    int stride = isf ? 64 : 192;

    float a0 = 0.f, a1 = 0.f, a2 = 0.f, a3 = 0.f;
    for (int k = 0; k < 64; k += 4) {
        float4 hv = *(const float4*)&hbuf[wid][k];
#pragma unroll
        for (int t = 0; t < 4; ++t) {
            float4 u = *(const float4*)p;
            p += stride;
            float hvt = ((const float*)&hv)[t];
            a0 += hvt * u.x; a1 += hvt * u.y; a2 += hvt * u.z; a3 += hvt * u.w;
        }
    }

    if (isf) {
        size_t d = (size_t)dst * 64 + cb;
        float4 cv = *(const float4*)&cbuf[wid][cb];
        atomicAdd(&fcs[d + 0], sigmoidf_(xf[d + 0] + a0) * cv.x);
        atomicAdd(&fcs[d + 1], sigmoidf_(xf[d + 1] + a1) * cv.y);
        atomicAdd(&fcs[d + 2], sigmoidf_(xf[d + 2] + a2) * cv.z);
        atomicAdd(&fcs[d + 3], sigmoidf_(xf[d + 3] + a3) * cv.w);
    } else {
        size_t d = (size_t)dst * 192 + cb;
        atomicAdd(&uh[d + 0], a0);
        atomicAdd(&uh[d + 1], a1);
        atomicAdd(&uh[d + 2], a2);
        atomicAdd(&uh[d + 3], a3);
    }
}

extern "C" void kernel_launch(void* const* d_in, const int* in_sizes, int n_in,
                              void* d_out, int out_size, void* d_ws, size_t ws_size,
                              hipStream_t stream) {
    const float* x      = (const float*)d_in[0];
    // d_in[1] = edge_src == arange(500, 52500) -> unused
    const int* edge_dst = (const int*)d_in[2];
    const int* mat_id   = (const int*)d_in[3];
    const float* Wiou   = (const float*)d_in[4];
    const float* biou   = (const float*)d_in[5];
    const float* Wf     = (const float*)d_in[6];
    const float* bfp    = (const float*)d_in[7];
    const float* Uiou   = (const float*)d_in[8];
    const float* Ufm    = (const float*)d_in[9];

    // ws layout (kept identical to R4/R5; uh/fcs/xf used only by fallback):
    // [uh NP*192 f32][fcs NP*64][xf NP*64][Wpk 65536 u16][tmp MAXEL*256 f32]
    // [Upack 32*32768 u16]
    // ints: [bin_off 192][ord 52000][childOff 36504][cursor 36500][bincnt 2560]
    //       [bincur 2560][childList 52000][bsum 144]
    float* uh  = (float*)d_ws;
    float* fcs = uh + (size_t)NP * 192;
    float* xf  = fcs + (size_t)NP * 64;
    unsigned short* Wpk = (unsigned short*)(xf + (size_t)NP * 64);
    float* tmp = (float*)(Wpk + 65536);
    unsigned short* Upack = (unsigned short*)(tmp + (size_t)MAXEL * 256);
    int* bin_off   = (int*)(Upack + (size_t)32 * 32768);
    int* ord       = bin_off + 192;
    int* childOff  = ord + NEDGE;
    int* cursor    = childOff + 36504;
    int* bincnt    = cursor + NP;
    int* bincur    = bincnt + 2560;
    int* childList = bincur + 2560;
    int* bsum      = childList + NEDGE;
    size_t need  = (size_t)((char*)(bsum + 144) - (char*)d_ws);
    size_t need2 = (size_t)((char*)tmp - (char*)d_ws);     // fallback: through Wpk
    int grouped = (ws_size >= need) ? 1 : 0;
    if (!grouped && ws_size < need2) return;               // cannot run at all

    float* out_h = (float*)d_out;            // f32 output: h then c
    float* out_c = out_h + (size_t)NN * 64;

    static const int noff[7] = {0, 500, 2500, 8500, 20500, 36500, 52500};

    if (grouped) {
        // setup (per replay; ws is re-poisoned): zero cursor(36500)+bincnt(2560) = 39060 ints
        zero_kernel<<<(9765 + 255) / 256, 256, 0, stream>>>((float*)cursor, 9765);
        histpack_kernel<<<364, 256, 0, stream>>>(edge_dst, mat_id, cursor, bincnt,
                                                 Uiou, Ufm, Wiou, Wf, Upack, Wpk);
        scan1_kernel<<<NSB, 256, 0, stream>>>(cursor, childOff, bsum);
        scan2_kernel<<<1, 256, 0, stream>>>(bsum, bincnt, bin_off, bincur);
        scan3_kernel<<<NSB, 256, 0, stream>>>(childOff, bsum, cursor);
        fill2_kernel<<<(NEDGE + 255) / 256, 256, 0, stream>>>(
            edge_dst, mat_id, cursor, childList, bincur, ord);

        for (int l = 5; l >= 0; --l) {
            int s0 = noff[l], s1 = noff[l + 1], nl = s1 - s0;
            int gather = (l != 5) ? 1 : 0;
            int gebase = gather ? (noff[l + 1] - E0) : 0;   // edges at level l+1
            projcell_kernel<<<(nl + 63) / 64, 256, 0, stream>>>(
                x, Wpk, biou, bfp, tmp, childOff, childList,
                out_h, out_c, s0, s1, gebase, gather);
            if (l >= 1) {
                int ebase = s0 - E0;
                int nbs = (nl + 2047) / 2048;   // wave-chunk slots per bin
                edge_gemm_kernel<<<32 * nbs, 256, 0, stream>>>(
                    out_h, Upack, bin_off, ord, tmp, l - 1, ebase, nbs);
            }
        }
    } else {
        int n4 = (int)((size_t)NP * 256 / 4);
        zero_kernel<<<(n4 + 255) / 256, 256, 0, stream>>>(uh, n4);
        wpack_kernel<<<128, 256, 0, stream>>>(Wiou, Wf, Wpk);
        xfproj_kernel<<<(NP + 63) / 64, 256, 0, stream>>>(x, Wpk, bfp, xf);
        for (int l = 5; l >= 0; --l) {
            int s0 = noff[l], s1 = noff[l + 1], nl = s1 - s0;
            projcell_legacy_kernel<<<(nl + 63) / 64, 256, 0, stream>>>(
                x, Wpk, biou, uh, fcs, out_h, out_c, s0, s1, (l != 5) ? 1 : 0);
            if (l >= 1) {
                edge_kernel<<<(nl + 3) / 4, 256, 0, stream>>>(
                    out_h, out_c, xf, uh, fcs, Uiou, Ufm, edge_dst, mat_id, s0, s1);
            }
        }
    }
}

// Round 7
// 330.312 us; speedup vs baseline: 3.0812x; 1.0787x over previous
//
#include <hip/hip_runtime.h>

#define NN 52500
#define NP 36500            // nodes with children (levels 0..4) = parents
#define E0 500              // edge e corresponds to src node n = e + 500
#define NEDGE 52000
#define NBINS 160           // 5 edge-levels x 32 matrices
#define MAXEL 16000         // max edges in one level
#define NSB 143             // scan blocks = ceil(NP/256)

__device__ __forceinline__ float sigmoidf_(float x) { return 1.f / (1.f + __expf(-x)); }
__device__ __forceinline__ float tanhf_(float x) {
    float e = __expf(-2.f * fabsf(x));
    return copysignf((1.f - e) / (1.f + e), x);
}

typedef __attribute__((ext_vector_type(8))) short bf16x8;
typedef __attribute__((ext_vector_type(4))) float f32x4;

__device__ __forceinline__ unsigned short f2bf_rne(float f) {
    unsigned int u = __float_as_uint(f);
    u += 0x7FFF + ((u >> 16) & 1);
    return (unsigned short)(u >> 16);
}

// load 8 consecutive f32, split each into bf16 hi + bf16 lo (compensated precision ~2^-17)
__device__ __forceinline__ void load_split(const float* p, bf16x8& hi, bf16x8& lo) {
    float4 a = *(const float4*)p;
    float4 b = *(const float4*)(p + 4);
    float v[8] = {a.x, a.y, a.z, a.w, b.x, b.y, b.z, b.w};
#pragma unroll
    for (int j = 0; j < 8; ++j) {
        unsigned short hu = f2bf_rne(v[j]);
        float hf = __uint_as_float((unsigned int)hu << 16);
        hi[j] = (short)hu;
        lo[j] = (short)f2bf_rne(v[j] - hf);
    }
}

__global__ __launch_bounds__(256) void zero_kernel(float* __restrict__ p, int n4) {
    int i = blockIdx.x * 256 + threadIdx.x;
    if (i < n4) ((float4*)p)[i] = (float4){0.f, 0.f, 0.f, 0.f};
}

// -------- W pack (8 elems/thread): Wiou (48 frags) + Wf (16 frags), hi/lo --------
// frag f=ct*4+kt; elem(lane,j) = W[ct*16+(lane&15)][kt*32+(lane>>4)*8+j]
// layout (ushort): [IOU_HI 0][IOU_LO 24576][F_HI 49152][F_LO 57344], total 65536
__device__ __forceinline__ void wpack8_body(int p8,
                                            const float* __restrict__ Wiou,
                                            const float* __restrict__ Wf,
                                            unsigned short* __restrict__ Wpk) {
    if (p8 >= 4096) return;
    int p0 = p8 * 8;
    int f = p0 >> 9, lane = (p0 >> 3) & 63;
    int l15 = lane & 15, quad = lane >> 4;
    const float* src;
    unsigned short *dh, *dl;
    if (f < 48) {
        int ct = f >> 2, kt = f & 3;
        src = Wiou + (size_t)(ct * 16 + l15) * 128 + kt * 32 + quad * 8;
        dh = Wpk + f * 512 + lane * 8;
        dl = Wpk + 24576 + f * 512 + lane * 8;
    } else {
        int ff = f - 48;
        int ct = ff >> 2, kt = ff & 3;
        src = Wf + (size_t)(ct * 16 + l15) * 128 + kt * 32 + quad * 8;
        dh = Wpk + 49152 + ff * 512 + lane * 8;
        dl = Wpk + 57344 + ff * 512 + lane * 8;
    }
    bf16x8 hv, lv;
#pragma unroll
    for (int j = 0; j < 8; ++j) {
        float v = src[j];
        unsigned short hu = f2bf_rne(v);
        float hf = __uint_as_float((unsigned int)hu << 16);
        hv[j] = (short)hu;
        lv[j] = (short)f2bf_rne(v - hf);
    }
    *(bf16x8*)dh = hv;
    *(bf16x8*)dl = lv;
}

// -------- merged setup: hist (blocks 0..203) | U pack LDS-staged (204..235) |
// -------- W pack (236..251). All numerics identical to the reference recipe.
__global__ __launch_bounds__(256) void histpack_kernel(
    const int* __restrict__ edge_dst, const int* __restrict__ mat_id,
    int* __restrict__ cnt, int* __restrict__ bincnt /*stride 16*/,
    const float* __restrict__ Uiou, const float* __restrict__ Ufm,
    const float* __restrict__ Wiou, const float* __restrict__ Wf,
    unsigned short* __restrict__ Upack, unsigned short* __restrict__ Wpk)
{
    __shared__ float sbuf[16384];      // 64 KB: U staging / hist local bins
    int b = blockIdx.x;
    if (b < 204) {
        int* lb = (int*)sbuf;          // 160 local bins
        for (int i = threadIdx.x; i < NBINS; i += 256) lb[i] = 0;
        __syncthreads();
        int e = b * 256 + threadIdx.x;
        if (e < NEDGE) {
            atomicAdd(&cnt[edge_dst[e]], 1);
            int L = (e >= 2000) + (e >= 8000) + (e >= 20000) + (e >= 36000);
            atomicAdd(&lb[L * 32 + mat_id[e]], 1);
        }
        __syncthreads();
        for (int i = threadIdx.x; i < NBINS; i += 256) {
            int v = lb[i];
            if (v) atomicAdd(&bincnt[i * 16], v);
        }
    } else if (b < 236) {
        int mid = b - 204;
        // stage U_iou[mid] (12288 f32) + U_f[mid] (4096 f32) into LDS, coalesced
        const float4* s0 = (const float4*)(Uiou + (size_t)mid * 12288);
        const float4* s1 = (const float4*)(Ufm + (size_t)mid * 4096);
        float4* d4 = (float4*)sbuf;
        for (int i = threadIdx.x; i < 4096; i += 256)
            d4[i] = (i < 3072) ? s0[i] : s1[i - 3072];
        __syncthreads();
        // emit fragments: frag f=ct*2+kt; elem(lane,j)=U[kt*32+(lane>>4)*8+j][ct*16+(lane&15)]
        unsigned short* dhi = Upack + (size_t)mid * 32768;
        unsigned short* dlo = dhi + 16384;
        for (int p0 = threadIdx.x * 8; p0 < 16384; p0 += 2048) {
            int f = p0 >> 9;
            int lane = (p0 >> 3) & 63;
            int kt = f & 1, ct = f >> 1;
            int kbase = kt * 32 + (lane >> 4) * 8;
            int col = ct * 16 + (lane & 15);
            bf16x8 hv, lv;
#pragma unroll
            for (int j = 0; j < 8; ++j) {
                int k = kbase + j;
                float v = (col < 192) ? sbuf[k * 192 + col]
                                      : sbuf[12288 + k * 64 + (col - 192)];
                unsigned short hu = f2bf_rne(v);
                float hf = __uint_as_float((unsigned int)hu << 16);
                hv[j] = (short)hu;
                lv[j] = (short)f2bf_rne(v - hf);
            }
            *(bf16x8*)&dhi[p0] = hv;
            *(bf16x8*)&dlo[p0] = lv;
        }
    } else {
        wpack8_body((b - 236) * 256 + threadIdx.x, Wiou, Wf, Wpk);
    }
}

// phase 1: per-block scan of counts -> in-block exclusive prefix + per-block sum
__global__ __launch_bounds__(256) void scan1_kernel(const int* __restrict__ cnt,
                                                    int* __restrict__ off,
                                                    int* __restrict__ bsum) {
    __shared__ int s[256];
    int t = threadIdx.x;
    int i = blockIdx.x * 256 + t;
    int v = (i < NP) ? cnt[i] : 0;
    s[t] = v;
    __syncthreads();
#pragma unroll
    for (int d = 1; d < 256; d <<= 1) {
        int u = (t >= d) ? s[t - d] : 0;
        __syncthreads();
        s[t] += u;
        __syncthreads();
    }
    if (i < NP) off[i] = s[t] - v;          // exclusive within block
    if (t == 255) bsum[blockIdx.x] = s[255];
}

// phase 2: exclusive scan of NSB block sums AND exclusive scan of 160 bin counts
__global__ __launch_bounds__(256) void scan2_kernel(int* __restrict__ bsum,
                                                    const int* __restrict__ bincnt,
                                                    int* __restrict__ bin_off,
                                                    int* __restrict__ bincur) {
    __shared__ int s[256];
    __shared__ int b[256];
    int t = threadIdx.x;
    int v = (t < NSB) ? bsum[t] : 0;
    int bv = (t < NBINS) ? bincnt[t * 16] : 0;
    s[t] = v;
    b[t] = bv;
    __syncthreads();
#pragma unroll
    for (int d = 1; d < 256; d <<= 1) {
        int u  = (t >= d) ? s[t - d] : 0;
        int ub = (t >= d) ? b[t - d] : 0;
        __syncthreads();
        s[t] += u;
        b[t] += ub;
        __syncthreads();
    }
    if (t < NSB) bsum[t] = s[t] - v;        // exclusive
    if (t < NBINS) {
        int o = b[t] - bv;                  // exclusive
        bin_off[t] = o;
        bincur[t * 16] = o;
    }
    if (t == 0) bin_off[NBINS] = NEDGE;
}

// phase 3: add block base, finalize childOff, init cursor
__global__ __launch_bounds__(256) void scan3_kernel(int* __restrict__ off,
                                                    const int* __restrict__ bsum,
                                                    int* __restrict__ cursor) {
    int i = blockIdx.x * 256 + threadIdx.x;
    if (i < NP) {
        int o = off[i] + bsum[blockIdx.x];
        off[i] = o;
        cursor[i] = o;
    }
    if (i == 0) off[NP] = NEDGE;            // total children == total edges
}

// CSR fill + bin ord fill in one pass (order within bin/parent irrelevant downstream)
__global__ __launch_bounds__(256) void fill2_kernel(const int* __restrict__ edge_dst,
                                                    const int* __restrict__ mat_id,
                                                    int* __restrict__ cursor,
                                                    int* __restrict__ childList,
                                                    int* __restrict__ bincur,
                                                    int* __restrict__ ord) {
    int e = blockIdx.x * 256 + threadIdx.x;
    if (e < NEDGE) {
        int pos = atomicAdd(&cursor[edge_dst[e]], 1);
        childList[pos] = e;
        int L = (e >= 2000) + (e >= 8000) + (e >= 20000) + (e >= 36000);
        int p2 = atomicAdd(&bincur[(L * 32 + mat_id[e]) * 16], 1);
        ord[p2] = e;
    }
}

__global__ __launch_bounds__(256) void wpack_kernel(
    const float* __restrict__ Wiou, const float* __restrict__ Wf,
    unsigned short* __restrict__ Wpk)
{
    wpack8_body(blockIdx.x * 256 + threadIdx.x, Wiou, Wf, Wpk);
}

// -------- FUSED per-level kernel: x_iou + x_f (MFMA, in-register) + CSR gather of
// children edge results from tmp + LSTM cell -> h,c. No uh/fcs/xf intermediates.
__global__ __launch_bounds__(256) void projcell_kernel(
    const float* __restrict__ x, const unsigned short* __restrict__ Wpk,
    const float* __restrict__ biou, const float* __restrict__ bfp,
    const float* __restrict__ tmp,
    const int* __restrict__ childOff, const int* __restrict__ childList,
    float* __restrict__ h_all, float* __restrict__ c_all,
    int s0, int s1, int ebase, int gather)
{
    int wave = threadIdx.x >> 6, lane = threadIdx.x & 63;
    int l15 = lane & 15, quad = lane >> 4;
    int rowBase = blockIdx.x * 64 + wave * 16;    // relative to s0

    int arow = s0 + rowBase + l15;
    if (arow >= s1) arow = s1 - 1;
    const float* ap = x + (size_t)arow * 128 + quad * 8;
    bf16x8 ahi[4], alo[4];
#pragma unroll
    for (int kt = 0; kt < 4; ++kt) load_split(ap + kt * 32, ahi[kt], alo[kt]);

    f32x4 acc[16];
#pragma unroll
    for (int ct = 0; ct < 16; ++ct) acc[ct] = (f32x4){0.f, 0.f, 0.f, 0.f};

    // x_iou: 12 col-tiles (192 cols)
#pragma unroll
    for (int ct = 0; ct < 12; ++ct) {
#pragma unroll
        for (int kt = 0; kt < 4; ++kt) {
            int f = ct * 4 + kt;
            const bf16x8 bhi = *(const bf16x8*)&Wpk[f * 512 + lane * 8];
            const bf16x8 blo = *(const bf16x8*)&Wpk[24576 + f * 512 + lane * 8];
            acc[ct] = __builtin_amdgcn_mfma_f32_16x16x32_bf16(ahi[kt], bhi, acc[ct], 0, 0, 0);
            acc[ct] = __builtin_amdgcn_mfma_f32_16x16x32_bf16(ahi[kt], blo, acc[ct], 0, 0, 0);
            acc[ct] = __builtin_amdgcn_mfma_f32_16x16x32_bf16(alo[kt], bhi, acc[ct], 0, 0, 0);
        }
    }
    // x_f: 4 col-tiles (64 cols), only needed when this level has children
    if (gather) {
#pragma unroll
        for (int g2 = 0; g2 < 4; ++g2) {
#pragma unroll
            for (int kt = 0; kt < 4; ++kt) {
                int f = g2 * 4 + kt;
                const bf16x8 bhi = *(const bf16x8*)&Wpk[49152 + f * 512 + lane * 8];
                const bf16x8 blo = *(const bf16x8*)&Wpk[57344 + f * 512 + lane * 8];
                acc[12 + g2] = __builtin_amdgcn_mfma_f32_16x16x32_bf16(ahi[kt], bhi, acc[12 + g2], 0, 0, 0);
                acc[12 + g2] = __builtin_amdgcn_mfma_f32_16x16x32_bf16(ahi[kt], blo, acc[12 + g2], 0, 0, 0);
                acc[12 + g2] = __builtin_amdgcn_mfma_f32_16x16x32_bf16(alo[kt], bhi, acc[12 + g2], 0, 0, 0);
            }
        }
    }

    // epilogue: lane (l15,quad) holds node n=rowBase+quad*4+r, cols j=16g+l15
#pragma unroll
    for (int r = 0; r < 4; ++r) {
        int n = s0 + rowBase + quad * 4 + r;
        if (n >= s1) continue;
        float ui[4] = {0.f, 0.f, 0.f, 0.f};
        float uo[4] = {0.f, 0.f, 0.f, 0.f};
        float uu[4] = {0.f, 0.f, 0.f, 0.f};
        float fc0[4] = {0.f, 0.f, 0.f, 0.f};
        if (gather) {
            int c0 = childOff[n], c1 = childOff[n + 1];
            float xfv[4];
#pragma unroll
            for (int g = 0; g < 4; ++g) xfv[g] = acc[12 + g][r] + bfp[g * 16 + l15];
            for (int ci = c0; ci < c1; ++ci) {
                int e = childList[ci];
                const float* tp = tmp + (size_t)(e - ebase) * 256;
                const float* cp = c_all + (size_t)(e + E0) * 64;
#pragma unroll
                for (int g = 0; g < 4; ++g) {
                    int j = g * 16 + l15;
                    ui[g] += tp[j];
                    uo[g] += tp[64 + j];
                    uu[g] += tp[128 + j];
                    fc0[g] += sigmoidf_(xfv[g] + tp[192 + j]) * cp[j];
                }
            }
        }
#pragma unroll
        for (int g = 0; g < 4; ++g) {
            int j = g * 16 + l15;
            float iv = acc[g][r] + biou[j];
            float ov = acc[4 + g][r] + biou[64 + j];
            float uv = acc[8 + g][r] + biou[128 + j];
            float cc = sigmoidf_(iv + ui[g]) * tanhf_(uv + uu[g]) + fc0[g];
            float hh = sigmoidf_(ov + uo[g]) * tanhf_(cc);
            h_all[(size_t)n * 64 + j] = hh;
            c_all[(size_t)n * 64 + j] = cc;
        }
    }
}

// -------- edge GEMM: LDS-free. Per (level,mid) bin, each WAVE handles 16-edge chunks,
// B-fragments streamed directly from L2-resident Upack. NO staging, NO barriers.
// tmp[e-ebase][256] = [Uh (192) | hf (64)] per edge, f32.
__global__ __launch_bounds__(256) void edge_gemm_kernel(
    const float* __restrict__ h_all,
    const unsigned short* __restrict__ Upack,
    const int* __restrict__ bin_off, const int* __restrict__ ord,
    float* __restrict__ tmp, int lvl, int ebase, int nbslots)
{
    int bin = lvl * 32 + (blockIdx.x & 31);
    int bslot = blockIdx.x >> 5;
    int off = bin_off[bin];
    int cnt = bin_off[bin + 1] - off;
    int mid = bin & 31;
    const unsigned short* Uhi = Upack + (size_t)mid * 32768;
    const unsigned short* Ulo = Uhi + 16384;

    int wid = threadIdx.x >> 6, lane = threadIdx.x & 63;
    int l15 = lane & 15, quad = lane >> 4;

    // wave-granular chunks of 16 edges
    for (int j0 = (bslot * 4 + wid) * 16; j0 < cnt; j0 += nbslots * 64) {
        int jc = j0 + l15; if (jc > cnt - 1) jc = cnt - 1;   // pad: duplicate last edge
        int e = ord[off + jc];
        const float* hp = h_all + (size_t)(e + E0) * 64 + quad * 8;
        bf16x8 ahi[2], alo[2];
        load_split(hp, ahi[0], alo[0]);
        load_split(hp + 32, ahi[1], alo[1]);

        f32x4 acc[16];
#pragma unroll
        for (int ct = 0; ct < 16; ++ct) acc[ct] = (f32x4){0.f, 0.f, 0.f, 0.f};

#pragma unroll
        for (int ct = 0; ct < 16; ++ct) {
#pragma unroll
            for (int kt = 0; kt < 2; ++kt) {
                int f = ct * 2 + kt;
                const bf16x8 bhi = *(const bf16x8*)&Uhi[f * 512 + lane * 8];
                const bf16x8 blo = *(const bf16x8*)&Ulo[f * 512 + lane * 8];
                acc[ct] = __builtin_amdgcn_mfma_f32_16x16x32_bf16(ahi[kt], bhi, acc[ct], 0, 0, 0);
                acc[ct] = __builtin_amdgcn_mfma_f32_16x16x32_bf16(ahi[kt], blo, acc[ct], 0, 0, 0);
                acc[ct] = __builtin_amdgcn_mfma_f32_16x16x32_bf16(alo[kt], bhi, acc[ct], 0, 0, 0);
            }
        }

        // epilogue: C row = quad*4+r (within the 16-edge chunk), col = ct*16+l15
#pragma unroll
        for (int r = 0; r < 4; ++r) {
            int jr = j0 + quad * 4 + r;
            if (jr < cnt) {
                int e2 = ord[off + jr];
                float* op = tmp + (size_t)(e2 - ebase) * 256 + l15;
#pragma unroll
                for (int ct = 0; ct < 16; ++ct) op[ct * 16] = acc[ct][r];
            }
        }
    }
}

// -------- legacy kernels (fallback when ws too small for grouped path) --------
__global__ __launch_bounds__(256) void xfproj_kernel(
    const float* __restrict__ x, const unsigned short* __restrict__ Wpk,
    const float* __restrict__ bfp, float* __restrict__ xf)
{
    int wave = threadIdx.x >> 6, lane = threadIdx.x & 63;
    int l15 = lane & 15, quad = lane >> 4;
    int rowBase = blockIdx.x * 64 + wave * 16;

    int arow = rowBase + l15;
    if (arow >= NP) arow = NP - 1;
    const float* ap = x + (size_t)arow * 128 + quad * 8;
    bf16x8 ahi[4], alo[4];
#pragma unroll
    for (int kt = 0; kt < 4; ++kt) load_split(ap + kt * 32, ahi[kt], alo[kt]);

    f32x4 acc[4];
#pragma unroll
    for (int ct = 0; ct < 4; ++ct) acc[ct] = (f32x4){0.f, 0.f, 0.f, 0.f};

#pragma unroll
    for (int ct = 0; ct < 4; ++ct) {
#pragma unroll
        for (int kt = 0; kt < 4; ++kt) {
            int f = ct * 4 + kt;
            const bf16x8 bhi = *(const bf16x8*)&Wpk[49152 + f * 512 + lane * 8];
            const bf16x8 blo = *(const bf16x8*)&Wpk[57344 + f * 512 + lane * 8];
            acc[ct] = __builtin_amdgcn_mfma_f32_16x16x32_bf16(ahi[kt], bhi, acc[ct], 0, 0, 0);
            acc[ct] = __builtin_amdgcn_mfma_f32_16x16x32_bf16(ahi[kt], blo, acc[ct], 0, 0, 0);
            acc[ct] = __builtin_amdgcn_mfma_f32_16x16x32_bf16(alo[kt], bhi, acc[ct], 0, 0, 0);
        }
    }

#pragma unroll
    for (int ct = 0; ct < 4; ++ct) {
        int col = ct * 16 + l15;
        float bias = bfp[col];
#pragma unroll
        for (int r = 0; r < 4; ++r) {
            int n = rowBase + quad * 4 + r;
            if (n < NP) xf[(size_t)n * 64 + col] = acc[ct][r] + bias;
        }
    }
}

__global__ __launch_bounds__(256) void projcell_legacy_kernel(
    const float* __restrict__ x, const unsigned short* __restrict__ Wpk,
    const float* __restrict__ biou,
    const float* __restrict__ uh, const float* __restrict__ fcs,
    float* __restrict__ h_all, float* __restrict__ c_all,
    int s0, int s1, int read_sums)
{
    int wave = threadIdx.x >> 6, lane = threadIdx.x & 63;
    int l15 = lane & 15, quad = lane >> 4;
    int rowBase = blockIdx.x * 64 + wave * 16;

    int arow = s0 + rowBase + l15;
    if (arow >= s1) arow = s1 - 1;
    const float* ap = x + (size_t)arow * 128 + quad * 8;
    bf16x8 ahi[4], alo[4];
#pragma unroll
    for (int kt = 0; kt < 4; ++kt) load_split(ap + kt * 32, ahi[kt], alo[kt]);

    f32x4 acc[12];
#pragma unroll
    for (int ct = 0; ct < 12; ++ct) acc[ct] = (f32x4){0.f, 0.f, 0.f, 0.f};

#pragma unroll
    for (int ct = 0; ct < 12; ++ct) {
#pragma unroll
        for (int kt = 0; kt < 4; ++kt) {
            int f = ct * 4 + kt;
            const bf16x8 bhi = *(const bf16x8*)&Wpk[f * 512 + lane * 8];
            const bf16x8 blo = *(const bf16x8*)&Wpk[24576 + f * 512 + lane * 8];
            acc[ct] = __builtin_amdgcn_mfma_f32_16x16x32_bf16(ahi[kt], bhi, acc[ct], 0, 0, 0);
            acc[ct] = __builtin_amdgcn_mfma_f32_16x16x32_bf16(ahi[kt], blo, acc[ct], 0, 0, 0);
            acc[ct] = __builtin_amdgcn_mfma_f32_16x16x32_bf16(alo[kt], bhi, acc[ct], 0, 0, 0);
        }
    }

#pragma unroll
    for (int g = 0; g < 4; ++g) {
        int j = g * 16 + l15;
        float bi = biou[j], bo = biou[64 + j], bu = biou[128 + j];
#pragma unroll
        for (int r = 0; r < 4; ++r) {
            int n = s0 + rowBase + quad * 4 + r;
            if (n < s1) {
                float iv = acc[g][r] + bi;
                float ov = acc[4 + g][r] + bo;
                float uv = acc[8 + g][r] + bu;
                float ui = 0.f, uo = 0.f, uu = 0.f, fc0 = 0.f;
                if (read_sums) {
                    size_t b = (size_t)n * 192;
                    ui = uh[b + j]; uo = uh[b + 64 + j]; uu = uh[b + 128 + j];
                    fc0 = fcs[(size_t)n * 64 + j];
                }
                float c = sigmoidf_(iv + ui) * tanhf_(uv + uu) + fc0;
                float h = sigmoidf_(ov + uo) * tanhf_(c);
                h_all[(size_t)n * 64 + j] = h;
                c_all[(size_t)n * 64 + j] = c;
            }
        }
    }
}

__global__ __launch_bounds__(256) void edge_kernel(
    const float* __restrict__ h_all, const float* __restrict__ c_all,
    const float* __restrict__ xf,
    float* __restrict__ uh, float* __restrict__ fcs,
    const float* __restrict__ Uiou, const float* __restrict__ Ufm,
    const int* __restrict__ edge_dst, const int* __restrict__ mat_id,
    int s0, int s1)
{
    __shared__ float hbuf[4][64];
    __shared__ float cbuf[4][64];
    int wid = threadIdx.x >> 6, lane = threadIdx.x & 63;
    int n = s0 + blockIdx.x * 4 + wid;
    if (n >= s1) return;

    hbuf[wid][lane] = h_all[(size_t)n * 64 + lane];
    cbuf[wid][lane] = c_all[(size_t)n * 64 + lane];

    int e = n - E0;
    int dst = edge_dst[e];
    int mid = mat_id[e];

    bool isf = (lane >= 48);
    int cb = isf ? 4 * (lane - 48) : 4 * lane;
    const float* p = isf ? (Ufm + (size_t)mid * 4096 + cb)
                         : (Uiou + (size_t)mid * 12288 + cb);
    int stride = isf ? 64 : 192;

    float a0 = 0.f, a1 = 0.f, a2 = 0.f, a3 = 0.f;
    for (int k = 0; k < 64; k += 4) {
        float4 hv = *(const float4*)&hbuf[wid][k];
#pragma unroll
        for (int t = 0; t < 4; ++t) {
            float4 u = *(const float4*)p;
            p += stride;
            float hvt = ((const float*)&hv)[t];
            a0 += hvt * u.x; a1 += hvt * u.y; a2 += hvt * u.z; a3 += hvt * u.w;
        }
    }

    if (isf) {
        size_t d = (size_t)dst * 64 + cb;
        float4 cv = *(const float4*)&cbuf[wid][cb];
        atomicAdd(&fcs[d + 0], sigmoidf_(xf[d + 0] + a0) * cv.x);
        atomicAdd(&fcs[d + 1], sigmoidf_(xf[d + 1] + a1) * cv.y);
        atomicAdd(&fcs[d + 2], sigmoidf_(xf[d + 2] + a2) * cv.z);
        atomicAdd(&fcs[d + 3], sigmoidf_(xf[d + 3] + a3) * cv.w);
    } else {
        size_t d = (size_t)dst * 192 + cb;
        atomicAdd(&uh[d + 0], a0);
        atomicAdd(&uh[d + 1], a1);
        atomicAdd(&uh[d + 2], a2);
        atomicAdd(&uh[d + 3], a3);
    }
}

extern "C" void kernel_launch(void* const* d_in, const int* in_sizes, int n_in,
                              void* d_out, int out_size, void* d_ws, size_t ws_size,
                              hipStream_t stream) {
    const float* x      = (const float*)d_in[0];
    // d_in[1] = edge_src == arange(500, 52500) -> unused
    const int* edge_dst = (const int*)d_in[2];
    const int* mat_id   = (const int*)d_in[3];
    const float* Wiou   = (const float*)d_in[4];
    const float* biou   = (const float*)d_in[5];
    const float* Wf     = (const float*)d_in[6];
    const float* bfp    = (const float*)d_in[7];
    const float* Uiou   = (const float*)d_in[8];
    const float* Ufm    = (const float*)d_in[9];

    // ws layout (kept identical to R4..R6; uh/fcs/xf used only by fallback):
    // [uh NP*192 f32][fcs NP*64][xf NP*64][Wpk 65536 u16][tmp MAXEL*256 f32]
    // [Upack 32*32768 u16]
    // ints: [bin_off 192][ord 52000][childOff 36504][cursor 36500][bincnt 2560]
    //       [bincur 2560][childList 52000][bsum 144]
    float* uh  = (float*)d_ws;
    float* fcs = uh + (size_t)NP * 192;
    float* xf  = fcs + (size_t)NP * 64;
    unsigned short* Wpk = (unsigned short*)(xf + (size_t)NP * 64);
    float* tmp = (float*)(Wpk + 65536);
    unsigned short* Upack = (unsigned short*)(tmp + (size_t)MAXEL * 256);
    int* bin_off   = (int*)(Upack + (size_t)32 * 32768);
    int* ord       = bin_off + 192;
    int* childOff  = ord + NEDGE;
    int* cursor    = childOff + 36504;
    int* bincnt    = cursor + NP;
    int* bincur    = bincnt + 2560;
    int* childList = bincur + 2560;
    int* bsum      = childList + NEDGE;
    size_t need  = (size_t)((char*)(bsum + 144) - (char*)d_ws);
    size_t need2 = (size_t)((char*)tmp - (char*)d_ws);     // fallback: through Wpk
    int grouped = (ws_size >= need) ? 1 : 0;
    if (!grouped && ws_size < need2) return;               // cannot run at all

    float* out_h = (float*)d_out;            // f32 output: h then c
    float* out_c = out_h + (size_t)NN * 64;

    static const int noff[7] = {0, 500, 2500, 8500, 20500, 36500, 52500};

    if (grouped) {
        // setup (per replay; ws is re-poisoned): zero cursor(36500)+bincnt(2560) = 39060 ints
        zero_kernel<<<(9765 + 255) / 256, 256, 0, stream>>>((float*)cursor, 9765);
        histpack_kernel<<<252, 256, 0, stream>>>(edge_dst, mat_id, cursor, bincnt,
                                                 Uiou, Ufm, Wiou, Wf, Upack, Wpk);
        scan1_kernel<<<NSB, 256, 0, stream>>>(cursor, childOff, bsum);
        scan2_kernel<<<1, 256, 0, stream>>>(bsum, bincnt, bin_off, bincur);
        scan3_kernel<<<NSB, 256, 0, stream>>>(childOff, bsum, cursor);
        fill2_kernel<<<(NEDGE + 255) / 256, 256, 0, stream>>>(
            edge_dst, mat_id, cursor, childList, bincur, ord);

        for (int l = 5; l >= 0; --l) {
            int s0 = noff[l], s1 = noff[l + 1], nl = s1 - s0;
            int gather = (l != 5) ? 1 : 0;
            int gebase = gather ? (noff[l + 1] - E0) : 0;   // edges at level l+1
            projcell_kernel<<<(nl + 63) / 64, 256, 0, stream>>>(
                x, Wpk, biou, bfp, tmp, childOff, childList,
                out_h, out_c, s0, s1, gebase, gather);
            if (l >= 1) {
                int ebase = s0 - E0;
                int nbs = (nl + 2047) / 2048;   // wave-chunk slots per bin
                edge_gemm_kernel<<<32 * nbs, 256, 0, stream>>>(
                    out_h, Upack, bin_off, ord, tmp, l - 1, ebase, nbs);
            }
        }
    } else {
        int n4 = (int)((size_t)NP * 256 / 4);
        zero_kernel<<<(n4 + 255) / 256, 256, 0, stream>>>(uh, n4);
        wpack_kernel<<<16, 256, 0, stream>>>(Wiou, Wf, Wpk);
        xfproj_kernel<<<(NP + 63) / 64, 256, 0, stream>>>(x, Wpk, bfp, xf);
        for (int l = 5; l >= 0; --l) {
            int s0 = noff[l], s1 = noff[l + 1], nl = s1 - s0;
            projcell_legacy_kernel<<<(nl + 63) / 64, 256, 0, stream>>>(
                x, Wpk, biou, uh, fcs, out_h, out_c, s0, s1, (l != 5) ? 1 : 0);
            if (l >= 1) {
                edge_kernel<<<(nl + 3) / 4, 256, 0, stream>>>(
                    out_h, out_c, xf, uh, fcs, Uiou, Ufm, edge_dst, mat_id, s0, s1);
            }
        }
    }
}